// Round 4
// baseline (1909.884 us; speedup 1.0000x reference)
//
#include <hip/hip_runtime.h>
#include <hip/hip_bf16.h>
#include <math.h>

using hbf = __hip_bfloat16;
typedef __bf16 bf16x8 __attribute__((ext_vector_type(8)));
typedef float f32x4 __attribute__((ext_vector_type(4)));

__device__ inline float wred(float v){
#pragma unroll
  for (int o = 32; o > 0; o >>= 1) v += __shfl_xor(v, o);
  return v;
}
__device__ inline float r16(float v){
  v += __shfl_xor(v, 1); v += __shfl_xor(v, 2);
  v += __shfl_xor(v, 4); v += __shfl_xor(v, 8);
  return v;
}
__device__ inline float fast_rcp(float x){
  float r; asm("v_rcp_f32 %0, %1" : "=v"(r) : "v"(x)); return r;
}
__device__ inline float d4(const float4& a, const float4& b){
  return a.x*b.x + a.y*b.y + a.z*b.z + a.w*b.w;
}

// ---------------- init: zero the two accumulators (ws is poisoned 0xAA once) ----
__global__ void k_init(float* scal){
  if (threadIdx.x < 2) scal[threadIdx.x] = 0.f;
}

// ---------------- fused distances / softmax / agg / vq loss --------------------
// one block per batch; 8 waves; wave w handles tokens n = it*8 + w
__global__ __launch_bounds__(512) void k_dist(const float* __restrict__ x,
    const float* __restrict__ vqcb, const float* __restrict__ agcb,
    hbf* __restrict__ aggbf, float* __restrict__ scal){
  __shared__ float cA[5376];
  __shared__ float cV[5376];
  __shared__ float sqA[7], sqV[7];
  const int tid = threadIdx.x, lane = tid & 63, wave = tid >> 6;
  const int b = blockIdx.x;
  for (int i = tid; i < 5376; i += 512){ cA[i] = agcb[i]; cV[i] = vqcb[i]; }
  __syncthreads();
  {
    int grp = tid >> 4, l16 = tid & 15;
    if (grp < 14){
      const float* s = (grp < 7) ? &cA[grp*768] : &cV[(grp-7)*768];
      float acc = 0.f;
      for (int j = l16; j < 768; j += 16) acc += s[j]*s[j];
      acc = r16(acc);
      if (l16 == 0){ if (grp < 7) sqA[grp] = acc; else sqV[grp-7] = acc; }
    }
  }
  __syncthreads();
  float sqAr[7], sqVr[7];
#pragma unroll
  for (int k = 0; k < 7; ++k){ sqAr[k] = sqA[k]; sqVr[k] = sqV[k]; }

  float4 aR[7][3];
#pragma unroll
  for (int k = 0; k < 7; ++k)
#pragma unroll
    for (int c = 0; c < 3; ++c) aR[k][c] = make_float4(0.f,0.f,0.f,0.f);
  float loss = 0.f;

  const float* xb = x + (size_t)b*196*768;
  float4 cx0, cx1, cx2, nx0, nx1, nx2;
  { const float* p = xb + (size_t)wave*768 + (lane<<2);
    cx0 = *(const float4*)(p); cx1 = *(const float4*)(p+256); cx2 = *(const float4*)(p+512); }
  for (int it = 0; it < 25; ++it){
    const int n = it*8 + wave;
    const int nn = n + 8;
    if (nn < 196){
      const float* p = xb + (size_t)nn*768 + (lane<<2);
      nx0 = *(const float4*)(p); nx1 = *(const float4*)(p+256); nx2 = *(const float4*)(p+512);
    }
    if (n < 196){
      float xsq = d4(cx0,cx0)+d4(cx1,cx1)+d4(cx2,cx2);
      float dA[7], dV[7];
#pragma unroll
      for (int k = 0; k < 7; ++k){
        const float4* pa = (const float4*)&cA[k*768];
        const float4* pv = (const float4*)&cV[k*768];
        float4 a0 = pa[lane], a1 = pa[64+lane], a2 = pa[128+lane];
        float4 q0 = pv[lane], q1 = pv[64+lane], q2 = pv[128+lane];
        dA[k] = d4(cx0,a0)+d4(cx1,a1)+d4(cx2,a2);
        dV[k] = d4(cx0,q0)+d4(cx1,q1)+d4(cx2,q2);
      }
      xsq = wred(xsq);
#pragma unroll
      for (int k = 0; k < 7; ++k){ dA[k] = wred(dA[k]); dV[k] = wred(dV[k]); }
      float lg[7], mx = -1e30f;
#pragma unroll
      for (int k = 0; k < 7; ++k){ lg[k] = 2.f*dA[k] - sqAr[k]; mx = fmaxf(mx, lg[k]); }
      float pr[7], ssum = 0.f;
#pragma unroll
      for (int k = 0; k < 7; ++k){ pr[k] = expf(lg[k]-mx); ssum += pr[k]; }
      const float inv = 1.f/ssum;
      float mn = 1e30f;
#pragma unroll
      for (int k = 0; k < 7; ++k) mn = fminf(mn, sqVr[k] - 2.f*dV[k]);
      loss += xsq + mn;
#pragma unroll
      for (int k = 0; k < 7; ++k){
        const float w = pr[k]*inv;
        aR[k][0].x += w*cx0.x; aR[k][0].y += w*cx0.y; aR[k][0].z += w*cx0.z; aR[k][0].w += w*cx0.w;
        aR[k][1].x += w*cx1.x; aR[k][1].y += w*cx1.y; aR[k][1].z += w*cx1.z; aR[k][1].w += w*cx1.w;
        aR[k][2].x += w*cx2.x; aR[k][2].y += w*cx2.y; aR[k][2].z += w*cx2.z; aR[k][2].w += w*cx2.w;
      }
    }
    cx0 = nx0; cx1 = nx1; cx2 = nx2;
  }
  __syncthreads();
  for (int i = tid; i < 5376; i += 512) cA[i] = 0.f;
  __syncthreads();
  for (int w = 0; w < 8; ++w){
    if (wave == w){
#pragma unroll
      for (int k = 0; k < 7; ++k)
#pragma unroll
        for (int c = 0; c < 3; ++c){
          float* p = &cA[k*768 + c*256 + (lane<<2)];
          p[0] += aR[k][c].x; p[1] += aR[k][c].y; p[2] += aR[k][c].z; p[3] += aR[k][c].w;
        }
    }
    __syncthreads();
  }
  for (int i = tid; i < 5376; i += 512) aggbf[(size_t)b*5376 + i] = __float2bfloat16(cA[i]);
  if (lane == 0) atomicAdd(&scal[0], loss);
}

// ---------------- Gram: G = X Xtr per batch, bf16 MFMA, X staged in LDS --------
__global__ __launch_bounds__(512) void k_gram(const float* __restrict__ x, float* __restrict__ G){
  __shared__ hbf Xs[208*104];
  const int tid = threadIdx.x, lane = tid & 63, wave = tid >> 6;
  const int b = blockIdx.x;
  const int l15 = lane & 15;
  const int fr0 = wave, fr1 = wave + 8;
  const bool f1 = (fr1 < 13);
  f32x4 acc0[13] = {};
  f32x4 acc1[13] = {};
  const float* xb = x + (size_t)b*196*768;
  for (int kc = 0; kc < 8; ++kc){
    __syncthreads();
    for (int u = tid; u < 4992; u += 512){
      const int r = u / 24, c4 = u - r*24;
      ushort4 val;
      if (r < 196){
        float4 f = *(const float4*)(xb + (size_t)r*768 + kc*96 + c4*4);
        hbf t0 = __float2bfloat16(f.x), t1 = __float2bfloat16(f.y);
        hbf t2 = __float2bfloat16(f.z), t3 = __float2bfloat16(f.w);
        val.x = *(const unsigned short*)&t0; val.y = *(const unsigned short*)&t1;
        val.z = *(const unsigned short*)&t2; val.w = *(const unsigned short*)&t3;
      } else { val.x = 0; val.y = 0; val.z = 0; val.w = 0; }
      *(ushort4*)&Xs[r*104 + c4*4] = val;
    }
    __syncthreads();
#pragma unroll
    for (int kk = 0; kk < 3; ++kk){
      const int ko = kk*32 + (lane>>4)*8;
      bf16x8 a0 = *(const bf16x8*)&Xs[(fr0*16 + l15)*104 + ko];
      bf16x8 a1 = f1 ? *(const bf16x8*)&Xs[(fr1*16 + l15)*104 + ko] : a0;
#pragma unroll
      for (int fc = 0; fc < 13; ++fc){
        bf16x8 bb = *(const bf16x8*)&Xs[(fc*16 + l15)*104 + ko];
        acc0[fc] = __builtin_amdgcn_mfma_f32_16x16x32_bf16(a0, bb, acc0[fc], 0, 0, 0);
        if (f1) acc1[fc] = __builtin_amdgcn_mfma_f32_16x16x32_bf16(a1, bb, acc1[fc], 0, 0, 0);
      }
    }
  }
  const size_t gb = (size_t)b*38416;
  const int cr = (lane>>4)*4;
#pragma unroll
  for (int fc = 0; fc < 13; ++fc){
    const int gc = fc*16 + l15;
    if (gc < 196){
#pragma unroll
      for (int r = 0; r < 4; ++r){
        const int gr = fr0*16 + cr + r;
        if (gr < 196) G[gb + (size_t)gr*196 + gc] = acc0[fc][r];
      }
      if (f1){
#pragma unroll
        for (int r = 0; r < 4; ++r){
          const int gr = fr1*16 + cr + r;
          if (gr < 196) G[gb + (size_t)gr*196 + gc] = acc1[fc][r];
        }
      }
    }
  }
}

// ---------------- eigen: Householder tridiag in LDS + Sturm bisection ----------
// 1024 threads (16 waves). 2 barriers per Householder step:
//  - pivot column read as contiguous row-k segment (A kept symmetric) into one
//    float4/lane; sigma/tau/v0 computed redundantly per wave (identical results)
//  - matvec: wave-per-row, float4 LDS reads, wred; barrier
//  - rank-2 update with wj = ww_raw - c2*vj folded in registers; barrier
__global__ __launch_bounds__(1024) void k_eigen(const float* __restrict__ G, float* __restrict__ scal){
  extern __shared__ float S[];
  float* A  = S;              // 196*197 = 38612
  float* ww = S + 38612;      // 200
  float* dd = S + 38812;      // 200
  float* ee = S + 39012;      // 200
  float* e2 = S + 39212;      // 200
  float* red2 = S + 39412;    // 16 (16B aligned)
  const int n = 196;
  const int tid = threadIdx.x, lane = tid & 63, wave = tid >> 6;
  const int b = blockIdx.x;
  const size_t gb = (size_t)b*38416;
  for (int u = tid; u < 38416; u += 1024){
    const int r = u / 196, c = u - r*196;
    A[r*197 + c] = G[gb + u];
  }
  __syncthreads();
  const int j0 = lane << 2;
  for (int k = 0; k <= n-3; ++k){
    const int base = k + 1, m = n - 1 - k;
    const float* rowk = &A[(size_t)k*197 + base];   // == column k below diag (symmetry)
    // ---- phase 0: per-wave redundant reflector computation, v in registers ----
    float4 xv = make_float4(0.f,0.f,0.f,0.f);
    if (j0 < m){
      if (j0 + 3 < m) xv = *(const float4*)(rowk + j0);
      else {
        xv.x = rowk[j0];
        if (j0+1 < m) xv.y = rowk[j0+1];
        if (j0+2 < m) xv.z = rowk[j0+2];
      }
    }
    const float x0 = rowk[0];                        // broadcast read
    float sig = ((lane==0)?0.f:xv.x*xv.x) + xv.y*xv.y + xv.z*xv.z + xv.w*xv.w;
    sig = wred(sig);
    float tau = 0.f, v0 = 0.f, alpha = x0;
    if (sig > 1e-20f){
      const float mu = sqrtf(x0*x0 + sig);
      alpha = (x0 > 0.f) ? -mu : mu;
      v0 = x0 - alpha;
      tau = 2.f/(sig + v0*v0);
    }
    if (tid == 0) ee[k] = alpha;
    float4 vj = xv; if (lane == 0) vj.x = v0;
    // ---- matvec: w_raw = tau * A v (wave per row) + per-wave v^T w partial ----
    if (tau != 0.f){
      float cpart = 0.f;
      for (int i = wave; i < m; i += 16){
        const float* Ar = &A[(size_t)(base+i)*197 + base];
        float s = 0.f;
        if (j0 < m){
          const float4 a4 = *(const float4*)(Ar + j0);
          s = a4.x*vj.x + a4.y*vj.y + a4.z*vj.z + a4.w*vj.w;
        }
        s = wred(s);
        if (lane == 0){
          const float wr = tau*s;
          ww[i] = wr;
          cpart += ((i==0) ? v0 : rowk[i])*wr;
        }
      }
      if (lane == 0) red2[wave] = cpart;
    }
    __syncthreads();                                 // B1
    // ---- rank-2 update: A -= v w^T + w v^T, w = w_raw - c2 v ----
    if (tau != 0.f){
      const float4* r2 = (const float4*)red2;
      const float4 q0 = r2[0], q1 = r2[1], q2 = r2[2], q3 = r2[3];
      const float vtw = (q0.x+q0.y+q0.z+q0.w) + (q1.x+q1.y+q1.z+q1.w)
                      + (q2.x+q2.y+q2.z+q2.w) + (q3.x+q3.y+q3.z+q3.w);
      const float c2 = 0.5f*tau*vtw;
      float4 wj = make_float4(0.f,0.f,0.f,0.f);
      if (j0 < m){                                   // ww sized 200: j0+3<=197 safe
        wj.x = ww[j0]   - c2*vj.x;
        wj.y = ww[j0+1] - c2*vj.y;
        wj.z = ww[j0+2] - c2*vj.z;
        wj.w = ww[j0+3] - c2*vj.w;
      }
      for (int i = wave; i < m; i += 16){
        const float vi = (i==0) ? v0 : rowk[i];      // broadcast reads
        const float wi = ww[i] - c2*vi;
        float* Ar = &A[(size_t)(base+i)*197 + base];
        if (j0 + 3 < m){
          float4 a4 = *(const float4*)(Ar + j0);
          a4.x -= vi*wj.x + wi*vj.x;
          a4.y -= vi*wj.y + wi*vj.y;
          a4.z -= vi*wj.z + wi*vj.z;
          a4.w -= vi*wj.w + wi*vj.w;
          *(float4*)(Ar + j0) = a4;
        } else if (j0 < m){
          Ar[j0] -= vi*wj.x + wi*vj.x;
          if (j0+1 < m) Ar[j0+1] -= vi*wj.y + wi*vj.y;
          if (j0+2 < m) Ar[j0+2] -= vi*wj.z + wi*vj.z;
        }
      }
    }
    __syncthreads();                                 // B2
  }
  if (tid < n) dd[tid] = A[(size_t)tid*197 + tid];
  if (tid == 0) ee[n-2] = A[(size_t)(n-1)*197 + (n-2)];
  __syncthreads();
  if (tid < n-1) e2[tid] = ee[tid]*ee[tid];
  __syncthreads();
  // Gershgorin bounds
  float lo = 1e30f, hi = -1e30f;
  if (tid < n){
    const float rr = ((tid > 0) ? fabsf(ee[tid-1]) : 0.f) + ((tid < n-1) ? fabsf(ee[tid]) : 0.f);
    lo = dd[tid] - rr; hi = dd[tid] + rr;
  }
  {
    float l2 = lo, h2 = hi;
#pragma unroll
    for (int o = 32; o > 0; o >>= 1){
      l2 = fminf(l2, __shfl_xor(l2, o));
      h2 = fmaxf(h2, __shfl_xor(h2, o));
    }
    if (lane == 0){ ww[wave] = l2; red2[wave] = h2; }
  }
  __syncthreads();
  float glo = ww[0], ghi = red2[0];
#pragma unroll
  for (int w2 = 1; w2 < 16; ++w2){ glo = fminf(glo, ww[w2]); ghi = fmaxf(ghi, red2[w2]); }
  __syncthreads();
  // Sturm bisection: thread tid finds the tid-th smallest eigenvalue
  float sv = 0.f;
  if (tid < n){
    float lob = glo, hib = ghi;
    for (int it2 = 0; it2 < 26; ++it2){
      const float mid = 0.5f*(lob + hib);
      float q = dd[0] - mid;
      int cnt = (q < 0.f) ? 1 : 0;
      for (int i = 1; i < n; ++i){
        const float r = fast_rcp(q);
        q = (dd[i] - mid) - e2[i-1]*r;
        q = (fabsf(q) < 1e-6f) ? -1e-6f : q;
        cnt += (q < 0.f) ? 1 : 0;
      }
      if (cnt <= tid) lob = mid; else hib = mid;
    }
    sv = sqrtf(fmaxf(0.5f*(lob + hib), 0.f));
  }
  __syncthreads();
  if (tid < n) ww[tid] = sv;
  __syncthreads();
  if (tid == 0){
    float tot = 0.f;
    for (int i = 0; i < n; ++i) tot += ww[i];
    const float thr = 0.99f*tot;
    float cs = 0.f; int rank = 0;
    for (int i = n-1; i >= 0; --i){ cs += ww[i]; rank += (cs <= thr) ? 1 : 0; }
    atomicAdd(&scal[1], (float)rank);
  }
}

// ---------------- transpose + f32->bf16 for weights ----------------------------
__global__ __launch_bounds__(256) void k_tr(const float* __restrict__ in, hbf* __restrict__ outp,
                                            int Rr, int Cc){
  __shared__ float t[32][33];
  const int tid = threadIdx.x;
  const int lc = tid & 31, lr = tid >> 5;
  const int c0 = blockIdx.x*32, r0 = blockIdx.y*32;
#pragma unroll
  for (int i = 0; i < 4; ++i)
    t[lr + i*8][lc] = in[(size_t)(r0 + lr + i*8)*Cc + c0 + lc];
  __syncthreads();
#pragma unroll
  for (int i = 0; i < 4; ++i)
    outp[(size_t)(c0 + lr + i*8)*Rr + r0 + lc] = __float2bfloat16(t[lc][lr + i*8]);
}

// ---------------- GEMM: A[M,K] * B^T[N,K], bf16 MFMA 16x16x32, 64x64 tiles ------
template<int EPI>
__global__ __launch_bounds__(256) void k_gemm(const hbf* __restrict__ Aa, const hbf* __restrict__ Bb,
    const float* __restrict__ bias, void* __restrict__ outp, int Mi, int Ni, int Ki){
  __shared__ hbf As[64*72];
  __shared__ hbf Bs[64*72];
  const int tid = threadIdx.x, lane = tid & 63, wave = tid >> 6;
  const int row0 = blockIdx.y*64, col0 = blockIdx.x*64;
  const int m0 = (wave >> 1)*32, n0 = (wave & 1)*32;
  const int l15 = lane & 15, lk = (lane >> 4)*8;
  const int sr = tid >> 3, sc = (tid & 7)*8;
  f32x4 acc00 = {}, acc01 = {}, acc10 = {}, acc11 = {};
  for (int kt = 0; kt < Ki; kt += 64){
    __syncthreads();
    *(uint4*)&As[sr*72 + sc]        = *(const uint4*)&Aa[(size_t)(row0+sr)*Ki + kt + sc];
    *(uint4*)&As[(sr+32)*72 + sc]   = *(const uint4*)&Aa[(size_t)(row0+sr+32)*Ki + kt + sc];
    *(uint4*)&Bs[sr*72 + sc]        = *(const uint4*)&Bb[(size_t)(col0+sr)*Ki + kt + sc];
    *(uint4*)&Bs[(sr+32)*72 + sc]   = *(const uint4*)&Bb[(size_t)(col0+sr+32)*Ki + kt + sc];
    __syncthreads();
#pragma unroll
    for (int kk = 0; kk < 2; ++kk){
      const int ko = kk*32 + lk;
      bf16x8 a0 = *(const bf16x8*)&As[(m0 + l15)*72 + ko];
      bf16x8 a1 = *(const bf16x8*)&As[(m0 + 16 + l15)*72 + ko];
      bf16x8 b0 = *(const bf16x8*)&Bs[(n0 + l15)*72 + ko];
      bf16x8 b1 = *(const bf16x8*)&Bs[(n0 + 16 + l15)*72 + ko];
      acc00 = __builtin_amdgcn_mfma_f32_16x16x32_bf16(a0, b0, acc00, 0, 0, 0);
      acc01 = __builtin_amdgcn_mfma_f32_16x16x32_bf16(a0, b1, acc01, 0, 0, 0);
      acc10 = __builtin_amdgcn_mfma_f32_16x16x32_bf16(a1, b0, acc10, 0, 0, 0);
      acc11 = __builtin_amdgcn_mfma_f32_16x16x32_bf16(a1, b1, acc11, 0, 0, 0);
    }
  }
  const int cr = (lane >> 4)*4;
#pragma unroll
  for (int i = 0; i < 2; ++i){
#pragma unroll
    for (int j = 0; j < 2; ++j){
      f32x4 av = (i == 0) ? ((j == 0) ? acc00 : acc01) : ((j == 0) ? acc10 : acc11);
      const int gcol = col0 + n0 + j*16 + l15;
#pragma unroll
      for (int r = 0; r < 4; ++r){
        const int grow = row0 + m0 + i*16 + cr + r;
        float v = av[r];
        if (EPI == 1){
          v += bias[gcol];
          v = 0.5f*v*(1.f + erff(v*0.70710678118654752f));
          ((hbf*)outp)[(size_t)grow*Ni + gcol] = __float2bfloat16(v);
        } else if (EPI == 2){
          v += bias[gcol];
          ((float*)outp)[(size_t)grow*Ni + gcol] = v;
        } else {
          ((float*)outp)[(size_t)grow*Ni + gcol] = v;
        }
      }
    }
  }
}

// ---------------- LayerNorm over 768, one wave per row --------------------------
__global__ __launch_bounds__(256) void k_ln(const float* __restrict__ h, const float* __restrict__ gam,
    const float* __restrict__ bet, hbf* __restrict__ hn){
  const int tid = threadIdx.x, lane = tid & 63, wave = tid >> 6;
  const int row = blockIdx.x*4 + wave;
  const float* hr = h + (size_t)row*768;
  const int off = lane*4;
  float4 v0 = *(const float4*)(hr + off);
  float4 v1 = *(const float4*)(hr + 256 + off);
  float4 v2 = *(const float4*)(hr + 512 + off);
  float s = v0.x+v0.y+v0.z+v0.w + v1.x+v1.y+v1.z+v1.w + v2.x+v2.y+v2.z+v2.w;
  s = wred(s);
  const float mu = s*(1.f/768.f);
  float q = 0.f;
  q += (v0.x-mu)*(v0.x-mu); q += (v0.y-mu)*(v0.y-mu); q += (v0.z-mu)*(v0.z-mu); q += (v0.w-mu)*(v0.w-mu);
  q += (v1.x-mu)*(v1.x-mu); q += (v1.y-mu)*(v1.y-mu); q += (v1.z-mu)*(v1.z-mu); q += (v1.w-mu)*(v1.w-mu);
  q += (v2.x-mu)*(v2.x-mu); q += (v2.y-mu)*(v2.y-mu); q += (v2.z-mu)*(v2.z-mu); q += (v2.w-mu)*(v2.w-mu);
  q = wred(q);
  const float rs = 1.f/sqrtf(q*(1.f/768.f) + 1e-5f);
  float4 g0 = *(const float4*)(gam + off), g1 = *(const float4*)(gam + 256 + off), g2 = *(const float4*)(gam + 512 + off);
  float4 t0 = *(const float4*)(bet + off), t1 = *(const float4*)(bet + 256 + off), t2 = *(const float4*)(bet + 512 + off);
  hbf* o = hn + (size_t)row*768;
  o[off+0] = __float2bfloat16((v0.x-mu)*rs*g0.x + t0.x);
  o[off+1] = __float2bfloat16((v0.y-mu)*rs*g0.y + t0.y);
  o[off+2] = __float2bfloat16((v0.z-mu)*rs*g0.z + t0.z);
  o[off+3] = __float2bfloat16((v0.w-mu)*rs*g0.w + t0.w);
  o[256+off+0] = __float2bfloat16((v1.x-mu)*rs*g1.x + t1.x);
  o[256+off+1] = __float2bfloat16((v1.y-mu)*rs*g1.y + t1.y);
  o[256+off+2] = __float2bfloat16((v1.z-mu)*rs*g1.z + t1.z);
  o[256+off+3] = __float2bfloat16((v1.w-mu)*rs*g1.w + t1.w);
  o[512+off+0] = __float2bfloat16((v2.x-mu)*rs*g2.x + t2.x);
  o[512+off+1] = __float2bfloat16((v2.y-mu)*rs*g2.y + t2.y);
  o[512+off+2] = __float2bfloat16((v2.z-mu)*rs*g2.z + t2.z);
  o[512+off+3] = __float2bfloat16((v2.w-mu)*rs*g2.w + t2.w);
}

// ---------------- head: normalize tok, grouped cosine logits, cls ---------------
__global__ __launch_bounds__(256) void k_head(const float* __restrict__ tok, const float* __restrict__ ce,
    const float* __restrict__ clsW, const float* __restrict__ clsb, const float* __restrict__ lgs,
    float* __restrict__ out){
  __shared__ float tkn[7*512];
  __shared__ float il[40];
  const int tid = threadIdx.x, lane = tid & 63, wave = tid >> 6;
  const int b = blockIdx.x;
  const float ls = lgs[0];
  for (int g = wave; g < 7; g += 4){
    const float* tr = tok + (size_t)(b*7 + g)*512;
    float4 u0 = *(const float4*)(tr + (lane<<3));
    float4 u1 = *(const float4*)(tr + (lane<<3) + 4);
    float s = d4(u0,u0) + d4(u1,u1);
    s = wred(s);
    const float inv = 1.f/sqrtf(s);
    float* dst = &tkn[g*512 + (lane<<3)];
    dst[0] = u0.x*inv; dst[1] = u0.y*inv; dst[2] = u0.z*inv; dst[3] = u0.w*inv;
    dst[4] = u1.x*inv; dst[5] = u1.y*inv; dst[6] = u1.z*inv; dst[7] = u1.w*inv;
  }
  __syncthreads();
  for (int c = wave; c < 34; c += 4){
    const int g = (c < 30) ? (c/5) : 6;
    const float* tp = &tkn[g*512 + (lane<<3)];
    const float* cp = ce + (size_t)c*512 + (lane<<3);
    float s = tp[0]*cp[0] + tp[1]*cp[1] + tp[2]*cp[2] + tp[3]*cp[3]
            + tp[4]*cp[4] + tp[5]*cp[5] + tp[6]*cp[6] + tp[7]*cp[7];
    s = wred(s);
    if (lane == 0){
      const float v = ls*s;
      il[c] = v;
      out[1792 + b*34 + c] = v;
    }
  }
  __syncthreads();
  if (tid < 7){
    float s = clsb[tid];
    for (int c = 0; c < 34; ++c) s += il[c]*clsW[c*7 + tid];
    out[b*7 + tid] = s;
  }
}

// ---------------- finalize scalars ----------------------------------------------
__global__ void k_fin(const float* __restrict__ scal, float* __restrict__ out){
  if (threadIdx.x == 0){
    out[10496] = 2.f*scal[0]/(float)(256*196*768);
    out[10497] = scal[1]*(1.f/256.f);
  }
}

extern "C" void kernel_launch(void* const* d_in, const int* in_sizes, int n_in,
                              void* d_out, int out_size, void* d_ws, size_t ws_size,
                              hipStream_t stream) {
  (void)in_sizes; (void)n_in; (void)out_size; (void)ws_size;
  const float* x    = (const float*)d_in[0];
  const float* vqcb = (const float*)d_in[1];
  const float* agcb = (const float*)d_in[2];
  const float* W1   = (const float*)d_in[3];
  const float* b1   = (const float*)d_in[4];
  const float* W2   = (const float*)d_in[5];
  const float* b2   = (const float*)d_in[6];
  const float* gam  = (const float*)d_in[7];
  const float* bet  = (const float*)d_in[8];
  const float* Wp   = (const float*)d_in[9];
  const float* ce   = (const float*)d_in[10];
  const float* clsW = (const float*)d_in[11];
  const float* clsb = (const float*)d_in[12];
  const float* lgs  = (const float*)d_in[13];
  float* out = (float*)d_out;
  char* w = (char*)d_ws;

  // workspace layout (~50 MB): scalars | G (reused later for MLP temps) | aggbf | W1t | W2t | Wpt
  float* scal  = (float*)w;
  float* G     = (float*)(w + 256);
  hbf*   aggbf = (hbf*)(w + 39338240ULL);
  hbf*   W1t   = (hbf*)(w + 42090752ULL);
  hbf*   W2t   = (hbf*)(w + 46809344ULL);
  hbf*   Wpt   = (hbf*)(w + 51527936ULL);
  // reuse of G region (G is dead after k_eigen; all consumers run after it):
  hbf*   h1    = (hbf*)(w + 256);
  float* hbuf  = (float*)(w + 256 + 16777216ULL);
  hbf*   hn    = (hbf*)(w + 256 + 25165824ULL);
  float* tok   = (float*)(w + 256 + 29360128ULL);

  k_init<<<dim3(1), dim3(64), 0, stream>>>(scal);
  k_dist<<<dim3(256), dim3(512), 0, stream>>>(x, vqcb, agcb, aggbf, scal);
  k_gram<<<dim3(256), dim3(512), 0, stream>>>(x, G);
  const int EIG_SMEM = (38612 + 4*200 + 16)*4; // 157,712 B
  hipFuncSetAttribute((const void*)k_eigen, hipFuncAttributeMaxDynamicSharedMemorySize, EIG_SMEM);
  k_eigen<<<dim3(256), dim3(1024), EIG_SMEM, stream>>>(G, scal);
  k_tr<<<dim3(96,24), dim3(256), 0, stream>>>(W1, W1t, 768, 3072);
  k_tr<<<dim3(24,96), dim3(256), 0, stream>>>(W2, W2t, 3072, 768);
  k_tr<<<dim3(16,24), dim3(256), 0, stream>>>(Wp, Wpt, 768, 512);
  k_gemm<1><<<dim3(48,28), dim3(256), 0, stream>>>(aggbf, W1t, b1, (void*)h1, 1792, 3072, 768);
  k_gemm<2><<<dim3(12,28), dim3(256), 0, stream>>>(h1, W2t, b2, (void*)hbuf, 1792, 768, 3072);
  k_ln<<<dim3(448), dim3(256), 0, stream>>>(hbuf, gam, bet, hn);
  k_gemm<3><<<dim3(8,28), dim3(256), 0, stream>>>(hn, Wpt, nullptr, (void*)tok, 1792, 512, 768);
  k_head<<<dim3(256), dim3(256), 0, stream>>>(tok, ce, clsW, clsb, lgs, out);
  k_fin<<<dim3(1), dim3(64), 0, stream>>>(scal, out);
}

// Round 5
// 1507.358 us; speedup vs baseline: 1.2670x; 1.2670x over previous
//
#include <hip/hip_runtime.h>
#include <hip/hip_bf16.h>
#include <math.h>

using hbf = __hip_bfloat16;
typedef __bf16 bf16x8 __attribute__((ext_vector_type(8)));
typedef float f32x4 __attribute__((ext_vector_type(4)));

__device__ inline float wred(float v){
#pragma unroll
  for (int o = 32; o > 0; o >>= 1) v += __shfl_xor(v, o);
  return v;
}
__device__ inline float r16(float v){
  v += __shfl_xor(v, 1); v += __shfl_xor(v, 2);
  v += __shfl_xor(v, 4); v += __shfl_xor(v, 8);
  return v;
}
__device__ inline float fast_rcp(float x){
  float r; asm("v_rcp_f32 %0, %1" : "=v"(r) : "v"(x)); return r;
}
__device__ inline float d4(const float4& a, const float4& b){
  return a.x*b.x + a.y*b.y + a.z*b.z + a.w*b.w;
}

// ---------------- init: zero the two accumulators (ws is poisoned 0xAA once) ----
__global__ void k_init(float* scal){
  if (threadIdx.x < 2) scal[threadIdx.x] = 0.f;
}

// ---------------- fused distances / softmax / agg / vq loss --------------------
// one block per batch; 8 waves; wave w handles tokens n = it*8 + w
__global__ __launch_bounds__(512) void k_dist(const float* __restrict__ x,
    const float* __restrict__ vqcb, const float* __restrict__ agcb,
    hbf* __restrict__ aggbf, float* __restrict__ scal){
  __shared__ float cA[5376];
  __shared__ float cV[5376];
  __shared__ float sqA[7], sqV[7];
  const int tid = threadIdx.x, lane = tid & 63, wave = tid >> 6;
  const int b = blockIdx.x;
  for (int i = tid; i < 5376; i += 512){ cA[i] = agcb[i]; cV[i] = vqcb[i]; }
  __syncthreads();
  {
    int grp = tid >> 4, l16 = tid & 15;
    if (grp < 14){
      const float* s = (grp < 7) ? &cA[grp*768] : &cV[(grp-7)*768];
      float acc = 0.f;
      for (int j = l16; j < 768; j += 16) acc += s[j]*s[j];
      acc = r16(acc);
      if (l16 == 0){ if (grp < 7) sqA[grp] = acc; else sqV[grp-7] = acc; }
    }
  }
  __syncthreads();
  float sqAr[7], sqVr[7];
#pragma unroll
  for (int k = 0; k < 7; ++k){ sqAr[k] = sqA[k]; sqVr[k] = sqV[k]; }

  float4 aR[7][3];
#pragma unroll
  for (int k = 0; k < 7; ++k)
#pragma unroll
    for (int c = 0; c < 3; ++c) aR[k][c] = make_float4(0.f,0.f,0.f,0.f);
  float loss = 0.f;

  const float* xb = x + (size_t)b*196*768;
  float4 cx0, cx1, cx2, nx0, nx1, nx2;
  { const float* p = xb + (size_t)wave*768 + (lane<<2);
    cx0 = *(const float4*)(p); cx1 = *(const float4*)(p+256); cx2 = *(const float4*)(p+512); }
  for (int it = 0; it < 25; ++it){
    const int n = it*8 + wave;
    const int nn = n + 8;
    if (nn < 196){
      const float* p = xb + (size_t)nn*768 + (lane<<2);
      nx0 = *(const float4*)(p); nx1 = *(const float4*)(p+256); nx2 = *(const float4*)(p+512);
    }
    if (n < 196){
      float xsq = d4(cx0,cx0)+d4(cx1,cx1)+d4(cx2,cx2);
      float dA[7], dV[7];
#pragma unroll
      for (int k = 0; k < 7; ++k){
        const float4* pa = (const float4*)&cA[k*768];
        const float4* pv = (const float4*)&cV[k*768];
        float4 a0 = pa[lane], a1 = pa[64+lane], a2 = pa[128+lane];
        float4 q0 = pv[lane], q1 = pv[64+lane], q2 = pv[128+lane];
        dA[k] = d4(cx0,a0)+d4(cx1,a1)+d4(cx2,a2);
        dV[k] = d4(cx0,q0)+d4(cx1,q1)+d4(cx2,q2);
      }
      xsq = wred(xsq);
#pragma unroll
      for (int k = 0; k < 7; ++k){ dA[k] = wred(dA[k]); dV[k] = wred(dV[k]); }
      float lg[7], mx = -1e30f;
#pragma unroll
      for (int k = 0; k < 7; ++k){ lg[k] = 2.f*dA[k] - sqAr[k]; mx = fmaxf(mx, lg[k]); }
      float pr[7], ssum = 0.f;
#pragma unroll
      for (int k = 0; k < 7; ++k){ pr[k] = expf(lg[k]-mx); ssum += pr[k]; }
      const float inv = 1.f/ssum;
      float mn = 1e30f;
#pragma unroll
      for (int k = 0; k < 7; ++k) mn = fminf(mn, sqVr[k] - 2.f*dV[k]);
      loss += xsq + mn;
#pragma unroll
      for (int k = 0; k < 7; ++k){
        const float w = pr[k]*inv;
        aR[k][0].x += w*cx0.x; aR[k][0].y += w*cx0.y; aR[k][0].z += w*cx0.z; aR[k][0].w += w*cx0.w;
        aR[k][1].x += w*cx1.x; aR[k][1].y += w*cx1.y; aR[k][1].z += w*cx1.z; aR[k][1].w += w*cx1.w;
        aR[k][2].x += w*cx2.x; aR[k][2].y += w*cx2.y; aR[k][2].z += w*cx2.z; aR[k][2].w += w*cx2.w;
      }
    }
    cx0 = nx0; cx1 = nx1; cx2 = nx2;
  }
  __syncthreads();
  for (int i = tid; i < 5376; i += 512) cA[i] = 0.f;
  __syncthreads();
  for (int w = 0; w < 8; ++w){
    if (wave == w){
#pragma unroll
      for (int k = 0; k < 7; ++k)
#pragma unroll
        for (int c = 0; c < 3; ++c){
          float* p = &cA[k*768 + c*256 + (lane<<2)];
          p[0] += aR[k][c].x; p[1] += aR[k][c].y; p[2] += aR[k][c].z; p[3] += aR[k][c].w;
        }
    }
    __syncthreads();
  }
  for (int i = tid; i < 5376; i += 512) aggbf[(size_t)b*5376 + i] = __float2bfloat16(cA[i]);
  if (lane == 0) atomicAdd(&scal[0], loss);
}

// ---------------- Gram: G = X Xtr per batch, bf16 MFMA, X staged in LDS --------
__global__ __launch_bounds__(512) void k_gram(const float* __restrict__ x, float* __restrict__ G){
  __shared__ hbf Xs[208*104];
  const int tid = threadIdx.x, lane = tid & 63, wave = tid >> 6;
  const int b = blockIdx.x;
  const int l15 = lane & 15;
  const int fr0 = wave, fr1 = wave + 8;
  const bool f1 = (fr1 < 13);
  f32x4 acc0[13] = {};
  f32x4 acc1[13] = {};
  const float* xb = x + (size_t)b*196*768;
  for (int kc = 0; kc < 8; ++kc){
    __syncthreads();
    for (int u = tid; u < 4992; u += 512){
      const int r = u / 24, c4 = u - r*24;
      ushort4 val;
      if (r < 196){
        float4 f = *(const float4*)(xb + (size_t)r*768 + kc*96 + c4*4);
        hbf t0 = __float2bfloat16(f.x), t1 = __float2bfloat16(f.y);
        hbf t2 = __float2bfloat16(f.z), t3 = __float2bfloat16(f.w);
        val.x = *(const unsigned short*)&t0; val.y = *(const unsigned short*)&t1;
        val.z = *(const unsigned short*)&t2; val.w = *(const unsigned short*)&t3;
      } else { val.x = 0; val.y = 0; val.z = 0; val.w = 0; }
      *(ushort4*)&Xs[r*104 + c4*4] = val;
    }
    __syncthreads();
#pragma unroll
    for (int kk = 0; kk < 3; ++kk){
      const int ko = kk*32 + (lane>>4)*8;
      bf16x8 a0 = *(const bf16x8*)&Xs[(fr0*16 + l15)*104 + ko];
      bf16x8 a1 = f1 ? *(const bf16x8*)&Xs[(fr1*16 + l15)*104 + ko] : a0;
#pragma unroll
      for (int fc = 0; fc < 13; ++fc){
        bf16x8 bb = *(const bf16x8*)&Xs[(fc*16 + l15)*104 + ko];
        acc0[fc] = __builtin_amdgcn_mfma_f32_16x16x32_bf16(a0, bb, acc0[fc], 0, 0, 0);
        if (f1) acc1[fc] = __builtin_amdgcn_mfma_f32_16x16x32_bf16(a1, bb, acc1[fc], 0, 0, 0);
      }
    }
  }
  const size_t gb = (size_t)b*38416;
  const int cr = (lane>>4)*4;
#pragma unroll
  for (int fc = 0; fc < 13; ++fc){
    const int gc = fc*16 + l15;
    if (gc < 196){
#pragma unroll
      for (int r = 0; r < 4; ++r){
        const int gr = fr0*16 + cr + r;
        if (gr < 196) G[gb + (size_t)gr*196 + gc] = acc0[fc][r];
      }
      if (f1){
#pragma unroll
        for (int r = 0; r < 4; ++r){
          const int gr = fr1*16 + cr + r;
          if (gr < 196) G[gb + (size_t)gr*196 + gc] = acc1[fc][r];
        }
      }
    }
  }
}

// ---------------- eigen: Householder tridiag in LDS + Sturm bisection ----------
// 1024 threads (16 waves), 2 barriers/step. A stored with stride 196 (16B-aligned
// rows). Columns tiled 4-aligned absolute: ONE float4 per lane covers all 196
// columns. Per-lane masks zero components outside (base, n); v0 inserted at the
// base component (lane 0). v_i/w_i cached in statically-unrolled register arrays.
__global__ __launch_bounds__(1024) void k_eigen(const float* __restrict__ G, float* __restrict__ scal){
  extern __shared__ float S[];
  float* A  = S;              // 196*196 = 38416
  float* ww = S + 38416;      // 200 (absolute-indexed w)
  float* dd = S + 38616;      // 200
  float* ee = S + 38816;      // 200
  float* e2 = S + 39016;      // 200
  float* red2 = S + 39216;    // 16 (16B-aligned)
  const int n = 196;
  const int tid = threadIdx.x, lane = tid & 63, wave = tid >> 6;
  const int b = blockIdx.x;
  {
    const float4* Gv = (const float4*)(G + (size_t)b*38416);
    float4* Av = (float4*)A;
    for (int u = tid; u < 9604; u += 1024) Av[u] = Gv[u];
  }
  __syncthreads();
  for (int k = 0; k <= n-3; ++k){
    const int base = k + 1, m = n - 1 - k;
    const int c0 = base & ~3, off = base - c0;
    const int jc = c0 + (lane << 2);               // absolute column of comp 0 (16B-aligned)
    const float* rowk2 = &A[(size_t)k*196];        // pivot row (== pivot column by symmetry)
    const float x0 = rowk2[base];                  // broadcast
    const float4 xv = *(const float4*)(rowk2 + jc);
    // reflector tail components, masked to (base, n)
    float4 vj;
    vj.x = (jc+0 > base && jc+0 < n) ? xv.x : 0.f;
    vj.y = (jc+1 > base && jc+1 < n) ? xv.y : 0.f;
    vj.z = (jc+2 > base && jc+2 < n) ? xv.z : 0.f;
    vj.w = (jc+3 > base && jc+3 < n) ? xv.w : 0.f;
    float sig = vj.x*vj.x + vj.y*vj.y + vj.z*vj.z + vj.w*vj.w;
    sig = wred(sig);
    float tau = 0.f, v0 = 0.f, alpha = x0;
    if (sig > 1e-20f){
      const float mu = sqrtf(x0*x0 + sig);
      alpha = (x0 > 0.f) ? -mu : mu;
      v0 = x0 - alpha;
      tau = 2.f/(sig + v0*v0);
    }
    if (tid == 0) ee[k] = alpha;
    if (lane == 0){                                // base component lives in lane 0
      if (off == 0) vj.x = v0;
      else if (off == 1) vj.y = v0;
      else if (off == 2) vj.z = v0;
      else vj.w = v0;
    }
    float vr_reg[13], wr_reg[13];
    // ---- matvec: w_raw = tau * A v (wave per row), cpart = partial v^T w ----
    if (tau != 0.f){
      float cpart = 0.f;
#pragma unroll
      for (int idx = 0; idx < 13; ++idx){
        const int i = wave + (idx << 4);
        if (i < m){
          const float* Ar = &A[(size_t)(base+i)*196];
          const float4 a4 = *(const float4*)(Ar + jc);
          float s = a4.x*vj.x + a4.y*vj.y + a4.z*vj.z + a4.w*vj.w;
          s = wred(s);
          const float wr = tau*s;
          const float vr = (i == 0) ? v0 : rowk2[base+i];
          vr_reg[idx] = vr; wr_reg[idx] = wr;
          cpart += vr*wr;
          if (lane == 0) ww[base+i] = wr;
        }
      }
      if (lane == 0) red2[wave] = cpart;
    }
    __syncthreads();                               // B1
    // ---- rank-2 update: A -= v w^T + w v^T, w = w_raw - c2 v ----
    if (tau != 0.f){
      const float4* r2 = (const float4*)red2;
      const float4 q0 = r2[0], q1 = r2[1], q2 = r2[2], q3 = r2[3];
      const float vtw = (q0.x+q0.y+q0.z+q0.w) + (q1.x+q1.y+q1.z+q1.w)
                      + (q2.x+q2.y+q2.z+q2.w) + (q3.x+q3.y+q3.z+q3.w);
      const float c2 = 0.5f*tau*vtw;
      const float4 w4 = *(const float4*)(ww + jc); // aligned; OOB lanes unused
      float4 wj;
      wj.x = (jc+0 >= base && jc+0 < n) ? (w4.x - c2*vj.x) : 0.f;
      wj.y = (jc+1 >= base && jc+1 < n) ? (w4.y - c2*vj.y) : 0.f;
      wj.z = (jc+2 >= base && jc+2 < n) ? (w4.z - c2*vj.z) : 0.f;
      wj.w = (jc+3 >= base && jc+3 < n) ? (w4.w - c2*vj.w) : 0.f;
      const bool fullw = (jc >= base) && (jc < n);
      const bool strad = (jc < base) && (jc + 4 > base);   // lane 0 when off>0
#pragma unroll
      for (int idx = 0; idx < 13; ++idx){
        const int i = wave + (idx << 4);
        if (i < m){
          const float vi = vr_reg[idx];
          const float wi = wr_reg[idx] - c2*vi;
          float* Ar = &A[(size_t)(base+i)*196];
          float4 a4 = *(const float4*)(Ar + jc);
          a4.x -= vi*wj.x + wi*vj.x;
          a4.y -= vi*wj.y + wi*vj.y;
          a4.z -= vi*wj.z + wi*vj.z;
          a4.w -= vi*wj.w + wi*vj.w;
          if (fullw){
            *(float4*)(Ar + jc) = a4;
          } else if (strad){
            if (off <= 1) Ar[jc+1] = a4.y;
            if (off <= 2) Ar[jc+2] = a4.z;
            Ar[jc+3] = a4.w;
          }
        }
      }
    }
    __syncthreads();                               // B2
  }
  if (tid < n) dd[tid] = A[(size_t)tid*196 + tid];
  if (tid == 0) ee[n-2] = A[(size_t)(n-1)*196 + (n-2)];
  __syncthreads();
  if (tid < n-1) e2[tid] = ee[tid]*ee[tid];
  __syncthreads();
  // Gershgorin bounds
  float lo = 1e30f, hi = -1e30f;
  if (tid < n){
    const float rr = ((tid > 0) ? fabsf(ee[tid-1]) : 0.f) + ((tid < n-1) ? fabsf(ee[tid]) : 0.f);
    lo = dd[tid] - rr; hi = dd[tid] + rr;
  }
  {
    float l2 = lo, h2 = hi;
#pragma unroll
    for (int o = 32; o > 0; o >>= 1){
      l2 = fminf(l2, __shfl_xor(l2, o));
      h2 = fmaxf(h2, __shfl_xor(h2, o));
    }
    if (lane == 0){ ww[wave] = l2; red2[wave] = h2; }
  }
  __syncthreads();
  float glo = ww[0], ghi = red2[0];
#pragma unroll
  for (int w2 = 1; w2 < 16; ++w2){ glo = fminf(glo, ww[w2]); ghi = fmaxf(ghi, red2[w2]); }
  __syncthreads();
  // Sturm bisection: thread tid finds the tid-th smallest eigenvalue
  float sv = 0.f;
  if (tid < n){
    float lob = glo, hib = ghi;
    for (int it2 = 0; it2 < 26; ++it2){
      const float mid = 0.5f*(lob + hib);
      float q = dd[0] - mid;
      int cnt = (q < 0.f) ? 1 : 0;
      for (int i = 1; i < n; ++i){
        const float r = fast_rcp(q);
        q = (dd[i] - mid) - e2[i-1]*r;
        q = (fabsf(q) < 1e-6f) ? -1e-6f : q;
        cnt += (q < 0.f) ? 1 : 0;
      }
      if (cnt <= tid) lob = mid; else hib = mid;
    }
    sv = sqrtf(fmaxf(0.5f*(lob + hib), 0.f));
  }
  __syncthreads();
  if (tid < n) ww[tid] = sv;
  __syncthreads();
  if (tid == 0){
    float tot = 0.f;
    for (int i = 0; i < n; ++i) tot += ww[i];
    const float thr = 0.99f*tot;
    float cs = 0.f; int rank = 0;
    for (int i = n-1; i >= 0; --i){ cs += ww[i]; rank += (cs <= thr) ? 1 : 0; }
    atomicAdd(&scal[1], (float)rank);
  }
}

// ---------------- transpose + f32->bf16 for weights ----------------------------
__global__ __launch_bounds__(256) void k_tr(const float* __restrict__ in, hbf* __restrict__ outp,
                                            int Rr, int Cc){
  __shared__ float t[32][33];
  const int tid = threadIdx.x;
  const int lc = tid & 31, lr = tid >> 5;
  const int c0 = blockIdx.x*32, r0 = blockIdx.y*32;
#pragma unroll
  for (int i = 0; i < 4; ++i)
    t[lr + i*8][lc] = in[(size_t)(r0 + lr + i*8)*Cc + c0 + lc];
  __syncthreads();
#pragma unroll
  for (int i = 0; i < 4; ++i)
    outp[(size_t)(c0 + lr + i*8)*Rr + r0 + lc] = __float2bfloat16(t[lc][lr + i*8]);
}

// ---------------- GEMM: A[M,K] * B^T[N,K], bf16 MFMA 16x16x32, 64x64 tiles ------
template<int EPI>
__global__ __launch_bounds__(256) void k_gemm(const hbf* __restrict__ Aa, const hbf* __restrict__ Bb,
    const float* __restrict__ bias, void* __restrict__ outp, int Mi, int Ni, int Ki){
  __shared__ hbf As[64*72];
  __shared__ hbf Bs[64*72];
  const int tid = threadIdx.x, lane = tid & 63, wave = tid >> 6;
  const int row0 = blockIdx.y*64, col0 = blockIdx.x*64;
  const int m0 = (wave >> 1)*32, n0 = (wave & 1)*32;
  const int l15 = lane & 15, lk = (lane >> 4)*8;
  const int sr = tid >> 3, sc = (tid & 7)*8;
  f32x4 acc00 = {}, acc01 = {}, acc10 = {}, acc11 = {};
  for (int kt = 0; kt < Ki; kt += 64){
    __syncthreads();
    *(uint4*)&As[sr*72 + sc]        = *(const uint4*)&Aa[(size_t)(row0+sr)*Ki + kt + sc];
    *(uint4*)&As[(sr+32)*72 + sc]   = *(const uint4*)&Aa[(size_t)(row0+sr+32)*Ki + kt + sc];
    *(uint4*)&Bs[sr*72 + sc]        = *(const uint4*)&Bb[(size_t)(col0+sr)*Ki + kt + sc];
    *(uint4*)&Bs[(sr+32)*72 + sc]   = *(const uint4*)&Bb[(size_t)(col0+sr+32)*Ki + kt + sc];
    __syncthreads();
#pragma unroll
    for (int kk = 0; kk < 2; ++kk){
      const int ko = kk*32 + lk;
      bf16x8 a0 = *(const bf16x8*)&As[(m0 + l15)*72 + ko];
      bf16x8 a1 = *(const bf16x8*)&As[(m0 + 16 + l15)*72 + ko];
      bf16x8 b0 = *(const bf16x8*)&Bs[(n0 + l15)*72 + ko];
      bf16x8 b1 = *(const bf16x8*)&Bs[(n0 + 16 + l15)*72 + ko];
      acc00 = __builtin_amdgcn_mfma_f32_16x16x32_bf16(a0, b0, acc00, 0, 0, 0);
      acc01 = __builtin_amdgcn_mfma_f32_16x16x32_bf16(a0, b1, acc01, 0, 0, 0);
      acc10 = __builtin_amdgcn_mfma_f32_16x16x32_bf16(a1, b0, acc10, 0, 0, 0);
      acc11 = __builtin_amdgcn_mfma_f32_16x16x32_bf16(a1, b1, acc11, 0, 0, 0);
    }
  }
  const int cr = (lane >> 4)*4;
#pragma unroll
  for (int i = 0; i < 2; ++i){
#pragma unroll
    for (int j = 0; j < 2; ++j){
      f32x4 av = (i == 0) ? ((j == 0) ? acc00 : acc01) : ((j == 0) ? acc10 : acc11);
      const int gcol = col0 + n0 + j*16 + l15;
#pragma unroll
      for (int r = 0; r < 4; ++r){
        const int grow = row0 + m0 + i*16 + cr + r;
        float v = av[r];
        if (EPI == 1){
          v += bias[gcol];
          v = 0.5f*v*(1.f + erff(v*0.70710678118654752f));
          ((hbf*)outp)[(size_t)grow*Ni + gcol] = __float2bfloat16(v);
        } else if (EPI == 2){
          v += bias[gcol];
          ((float*)outp)[(size_t)grow*Ni + gcol] = v;
        } else {
          ((float*)outp)[(size_t)grow*Ni + gcol] = v;
        }
      }
    }
  }
}

// ---------------- LayerNorm over 768, one wave per row --------------------------
__global__ __launch_bounds__(256) void k_ln(const float* __restrict__ h, const float* __restrict__ gam,
    const float* __restrict__ bet, hbf* __restrict__ hn){
  const int tid = threadIdx.x, lane = tid & 63, wave = tid >> 6;
  const int row = blockIdx.x*4 + wave;
  const float* hr = h + (size_t)row*768;
  const int off = lane*4;
  float4 v0 = *(const float4*)(hr + off);
  float4 v1 = *(const float4*)(hr + 256 + off);
  float4 v2 = *(const float4*)(hr + 512 + off);
  float s = v0.x+v0.y+v0.z+v0.w + v1.x+v1.y+v1.z+v1.w + v2.x+v2.y+v2.z+v2.w;
  s = wred(s);
  const float mu = s*(1.f/768.f);
  float q = 0.f;
  q += (v0.x-mu)*(v0.x-mu); q += (v0.y-mu)*(v0.y-mu); q += (v0.z-mu)*(v0.z-mu); q += (v0.w-mu)*(v0.w-mu);
  q += (v1.x-mu)*(v1.x-mu); q += (v1.y-mu)*(v1.y-mu); q += (v1.z-mu)*(v1.z-mu); q += (v1.w-mu)*(v1.w-mu);
  q += (v2.x-mu)*(v2.x-mu); q += (v2.y-mu)*(v2.y-mu); q += (v2.z-mu)*(v2.z-mu); q += (v2.w-mu)*(v2.w-mu);
  q = wred(q);
  const float rs = 1.f/sqrtf(q*(1.f/768.f) + 1e-5f);
  float4 g0 = *(const float4*)(gam + off), g1 = *(const float4*)(gam + 256 + off), g2 = *(const float4*)(gam + 512 + off);
  float4 t0 = *(const float4*)(bet + off), t1 = *(const float4*)(bet + 256 + off), t2 = *(const float4*)(bet + 512 + off);
  hbf* o = hn + (size_t)row*768;
  o[off+0] = __float2bfloat16((v0.x-mu)*rs*g0.x + t0.x);
  o[off+1] = __float2bfloat16((v0.y-mu)*rs*g0.y + t0.y);
  o[off+2] = __float2bfloat16((v0.z-mu)*rs*g0.z + t0.z);
  o[off+3] = __float2bfloat16((v0.w-mu)*rs*g0.w + t0.w);
  o[256+off+0] = __float2bfloat16((v1.x-mu)*rs*g1.x + t1.x);
  o[256+off+1] = __float2bfloat16((v1.y-mu)*rs*g1.y + t1.y);
  o[256+off+2] = __float2bfloat16((v1.z-mu)*rs*g1.z + t1.z);
  o[256+off+3] = __float2bfloat16((v1.w-mu)*rs*g1.w + t1.w);
  o[512+off+0] = __float2bfloat16((v2.x-mu)*rs*g2.x + t2.x);
  o[512+off+1] = __float2bfloat16((v2.y-mu)*rs*g2.y + t2.y);
  o[512+off+2] = __float2bfloat16((v2.z-mu)*rs*g2.z + t2.z);
  o[512+off+3] = __float2bfloat16((v2.w-mu)*rs*g2.w + t2.w);
}

// ---------------- head: normalize tok, grouped cosine logits, cls ---------------
__global__ __launch_bounds__(256) void k_head(const float* __restrict__ tok, const float* __restrict__ ce,
    const float* __restrict__ clsW, const float* __restrict__ clsb, const float* __restrict__ lgs,
    float* __restrict__ out){
  __shared__ float tkn[7*512];
  __shared__ float il[40];
  const int tid = threadIdx.x, lane = tid & 63, wave = tid >> 6;
  const int b = blockIdx.x;
  const float ls = lgs[0];
  for (int g = wave; g < 7; g += 4){
    const float* tr = tok + (size_t)(b*7 + g)*512;
    float4 u0 = *(const float4*)(tr + (lane<<3));
    float4 u1 = *(const float4*)(tr + (lane<<3) + 4);
    float s = d4(u0,u0) + d4(u1,u1);
    s = wred(s);
    const float inv = 1.f/sqrtf(s);
    float* dst = &tkn[g*512 + (lane<<3)];
    dst[0] = u0.x*inv; dst[1] = u0.y*inv; dst[2] = u0.z*inv; dst[3] = u0.w*inv;
    dst[4] = u1.x*inv; dst[5] = u1.y*inv; dst[6] = u1.z*inv; dst[7] = u1.w*inv;
  }
  __syncthreads();
  for (int c = wave; c < 34; c += 4){
    const int g = (c < 30) ? (c/5) : 6;
    const float* tp = &tkn[g*512 + (lane<<3)];
    const float* cp = ce + (size_t)c*512 + (lane<<3);
    float s = tp[0]*cp[0] + tp[1]*cp[1] + tp[2]*cp[2] + tp[3]*cp[3]
            + tp[4]*cp[4] + tp[5]*cp[5] + tp[6]*cp[6] + tp[7]*cp[7];
    s = wred(s);
    if (lane == 0){
      const float v = ls*s;
      il[c] = v;
      out[1792 + b*34 + c] = v;
    }
  }
  __syncthreads();
  if (tid < 7){
    float s = clsb[tid];
    for (int c = 0; c < 34; ++c) s += il[c]*clsW[c*7 + tid];
    out[b*7 + tid] = s;
  }
}

// ---------------- finalize scalars ----------------------------------------------
__global__ void k_fin(const float* __restrict__ scal, float* __restrict__ out){
  if (threadIdx.x == 0){
    out[10496] = 2.f*scal[0]/(float)(256*196*768);
    out[10497] = scal[1]*(1.f/256.f);
  }
}

extern "C" void kernel_launch(void* const* d_in, const int* in_sizes, int n_in,
                              void* d_out, int out_size, void* d_ws, size_t ws_size,
                              hipStream_t stream) {
  (void)in_sizes; (void)n_in; (void)out_size; (void)ws_size;
  const float* x    = (const float*)d_in[0];
  const float* vqcb = (const float*)d_in[1];
  const float* agcb = (const float*)d_in[2];
  const float* W1   = (const float*)d_in[3];
  const float* b1   = (const float*)d_in[4];
  const float* W2   = (const float*)d_in[5];
  const float* b2   = (const float*)d_in[6];
  const float* gam  = (const float*)d_in[7];
  const float* bet  = (const float*)d_in[8];
  const float* Wp   = (const float*)d_in[9];
  const float* ce   = (const float*)d_in[10];
  const float* clsW = (const float*)d_in[11];
  const float* clsb = (const float*)d_in[12];
  const float* lgs  = (const float*)d_in[13];
  float* out = (float*)d_out;
  char* w = (char*)d_ws;

  // workspace layout (~50 MB): scalars | G (reused later for MLP temps) | aggbf | W1t | W2t | Wpt
  float* scal  = (float*)w;
  float* G     = (float*)(w + 256);
  hbf*   aggbf = (hbf*)(w + 39338240ULL);
  hbf*   W1t   = (hbf*)(w + 42090752ULL);
  hbf*   W2t   = (hbf*)(w + 46809344ULL);
  hbf*   Wpt   = (hbf*)(w + 51527936ULL);
  // reuse of G region (G is dead after k_eigen; all consumers run after it):
  hbf*   h1    = (hbf*)(w + 256);
  float* hbuf  = (float*)(w + 256 + 16777216ULL);
  hbf*   hn    = (hbf*)(w + 256 + 25165824ULL);
  float* tok   = (float*)(w + 256 + 29360128ULL);

  k_init<<<dim3(1), dim3(64), 0, stream>>>(scal);
  k_dist<<<dim3(256), dim3(512), 0, stream>>>(x, vqcb, agcb, aggbf, scal);
  k_gram<<<dim3(256), dim3(512), 0, stream>>>(x, G);
  const int EIG_SMEM = (38416 + 4*200 + 16)*4; // 156,928 B
  hipFuncSetAttribute((const void*)k_eigen, hipFuncAttributeMaxDynamicSharedMemorySize, EIG_SMEM);
  k_eigen<<<dim3(256), dim3(1024), EIG_SMEM, stream>>>(G, scal);
  k_tr<<<dim3(96,24), dim3(256), 0, stream>>>(W1, W1t, 768, 3072);
  k_tr<<<dim3(24,96), dim3(256), 0, stream>>>(W2, W2t, 3072, 768);
  k_tr<<<dim3(16,24), dim3(256), 0, stream>>>(Wp, Wpt, 768, 512);
  k_gemm<1><<<dim3(48,28), dim3(256), 0, stream>>>(aggbf, W1t, b1, (void*)h1, 1792, 3072, 768);
  k_gemm<2><<<dim3(12,28), dim3(256), 0, stream>>>(h1, W2t, b2, (void*)hbuf, 1792, 768, 3072);
  k_ln<<<dim3(448), dim3(256), 0, stream>>>(hbuf, gam, bet, hn);
  k_gemm<3><<<dim3(8,28), dim3(256), 0, stream>>>(hn, Wpt, nullptr, (void*)tok, 1792, 512, 768);
  k_head<<<dim3(256), dim3(256), 0, stream>>>(tok, ce, clsW, clsb, lgs, out);
  k_fin<<<dim3(1), dim3(64), 0, stream>>>(scal, out);
}

// Round 6
// 1161.199 us; speedup vs baseline: 1.6448x; 1.2981x over previous
//
#include <hip/hip_runtime.h>
#include <hip/hip_bf16.h>
#include <math.h>

using hbf = __hip_bfloat16;
typedef __bf16 bf16x8 __attribute__((ext_vector_type(8)));
typedef float f32x4 __attribute__((ext_vector_type(4)));

__device__ inline float wred(float v){
#pragma unroll
  for (int o = 32; o > 0; o >>= 1) v += __shfl_xor(v, o);
  return v;
}
__device__ inline float r16(float v){
  v += __shfl_xor(v, 1); v += __shfl_xor(v, 2);
  v += __shfl_xor(v, 4); v += __shfl_xor(v, 8);
  return v;
}
__device__ inline float fast_rcp(float x){
  float r; asm("v_rcp_f32 %0, %1" : "=v"(r) : "v"(x)); return r;
}
__device__ inline float d4(const float4& a, const float4& b){
  return a.x*b.x + a.y*b.y + a.z*b.z + a.w*b.w;
}

// ---------------- init: zero the two accumulators (ws is poisoned 0xAA once) ----
__global__ void k_init(float* scal){
  if (threadIdx.x < 2) scal[threadIdx.x] = 0.f;
}

// ---------------- fused distances / softmax / agg / vq loss --------------------
// one block per batch; 8 waves; wave w handles tokens n = it*8 + w
__global__ __launch_bounds__(512) void k_dist(const float* __restrict__ x,
    const float* __restrict__ vqcb, const float* __restrict__ agcb,
    hbf* __restrict__ aggbf, float* __restrict__ scal){
  __shared__ float cA[5376];
  __shared__ float cV[5376];
  __shared__ float sqA[7], sqV[7];
  const int tid = threadIdx.x, lane = tid & 63, wave = tid >> 6;
  const int b = blockIdx.x;
  for (int i = tid; i < 5376; i += 512){ cA[i] = agcb[i]; cV[i] = vqcb[i]; }
  __syncthreads();
  {
    int grp = tid >> 4, l16 = tid & 15;
    if (grp < 14){
      const float* s = (grp < 7) ? &cA[grp*768] : &cV[(grp-7)*768];
      float acc = 0.f;
      for (int j = l16; j < 768; j += 16) acc += s[j]*s[j];
      acc = r16(acc);
      if (l16 == 0){ if (grp < 7) sqA[grp] = acc; else sqV[grp-7] = acc; }
    }
  }
  __syncthreads();
  float sqAr[7], sqVr[7];
#pragma unroll
  for (int k = 0; k < 7; ++k){ sqAr[k] = sqA[k]; sqVr[k] = sqV[k]; }

  float4 aR[7][3];
#pragma unroll
  for (int k = 0; k < 7; ++k)
#pragma unroll
    for (int c = 0; c < 3; ++c) aR[k][c] = make_float4(0.f,0.f,0.f,0.f);
  float loss = 0.f;

  const float* xb = x + (size_t)b*196*768;
  float4 cx0, cx1, cx2, nx0, nx1, nx2;
  { const float* p = xb + (size_t)wave*768 + (lane<<2);
    cx0 = *(const float4*)(p); cx1 = *(const float4*)(p+256); cx2 = *(const float4*)(p+512); }
  for (int it = 0; it < 25; ++it){
    const int n = it*8 + wave;
    const int nn = n + 8;
    if (nn < 196){
      const float* p = xb + (size_t)nn*768 + (lane<<2);
      nx0 = *(const float4*)(p); nx1 = *(const float4*)(p+256); nx2 = *(const float4*)(p+512);
    }
    if (n < 196){
      float xsq = d4(cx0,cx0)+d4(cx1,cx1)+d4(cx2,cx2);
      float dA[7], dV[7];
#pragma unroll
      for (int k = 0; k < 7; ++k){
        const float4* pa = (const float4*)&cA[k*768];
        const float4* pv = (const float4*)&cV[k*768];
        float4 a0 = pa[lane], a1 = pa[64+lane], a2 = pa[128+lane];
        float4 q0 = pv[lane], q1 = pv[64+lane], q2 = pv[128+lane];
        dA[k] = d4(cx0,a0)+d4(cx1,a1)+d4(cx2,a2);
        dV[k] = d4(cx0,q0)+d4(cx1,q1)+d4(cx2,q2);
      }
      xsq = wred(xsq);
#pragma unroll
      for (int k = 0; k < 7; ++k){ dA[k] = wred(dA[k]); dV[k] = wred(dV[k]); }
      float lg[7], mx = -1e30f;
#pragma unroll
      for (int k = 0; k < 7; ++k){ lg[k] = 2.f*dA[k] - sqAr[k]; mx = fmaxf(mx, lg[k]); }
      float pr[7], ssum = 0.f;
#pragma unroll
      for (int k = 0; k < 7; ++k){ pr[k] = expf(lg[k]-mx); ssum += pr[k]; }
      const float inv = 1.f/ssum;
      float mn = 1e30f;
#pragma unroll
      for (int k = 0; k < 7; ++k) mn = fminf(mn, sqVr[k] - 2.f*dV[k]);
      loss += xsq + mn;
#pragma unroll
      for (int k = 0; k < 7; ++k){
        const float w = pr[k]*inv;
        aR[k][0].x += w*cx0.x; aR[k][0].y += w*cx0.y; aR[k][0].z += w*cx0.z; aR[k][0].w += w*cx0.w;
        aR[k][1].x += w*cx1.x; aR[k][1].y += w*cx1.y; aR[k][1].z += w*cx1.z; aR[k][1].w += w*cx1.w;
        aR[k][2].x += w*cx2.x; aR[k][2].y += w*cx2.y; aR[k][2].z += w*cx2.z; aR[k][2].w += w*cx2.w;
      }
    }
    cx0 = nx0; cx1 = nx1; cx2 = nx2;
  }
  __syncthreads();
  for (int i = tid; i < 5376; i += 512) cA[i] = 0.f;
  __syncthreads();
  for (int w = 0; w < 8; ++w){
    if (wave == w){
#pragma unroll
      for (int k = 0; k < 7; ++k)
#pragma unroll
        for (int c = 0; c < 3; ++c){
          float* p = &cA[k*768 + c*256 + (lane<<2)];
          p[0] += aR[k][c].x; p[1] += aR[k][c].y; p[2] += aR[k][c].z; p[3] += aR[k][c].w;
        }
    }
    __syncthreads();
  }
  for (int i = tid; i < 5376; i += 512) aggbf[(size_t)b*5376 + i] = __float2bfloat16(cA[i]);
  if (lane == 0) atomicAdd(&scal[0], loss);
}

// ---------------- Gram: G = X Xtr per batch, bf16 MFMA, X staged in LDS --------
__global__ __launch_bounds__(512) void k_gram(const float* __restrict__ x, float* __restrict__ G){
  __shared__ hbf Xs[208*104];
  const int tid = threadIdx.x, lane = tid & 63, wave = tid >> 6;
  const int b = blockIdx.x;
  const int l15 = lane & 15;
  const int fr0 = wave, fr1 = wave + 8;
  const bool f1 = (fr1 < 13);
  f32x4 acc0[13] = {};
  f32x4 acc1[13] = {};
  const float* xb = x + (size_t)b*196*768;
  for (int kc = 0; kc < 8; ++kc){
    __syncthreads();
    for (int u = tid; u < 4992; u += 512){
      const int r = u / 24, c4 = u - r*24;
      ushort4 val;
      if (r < 196){
        float4 f = *(const float4*)(xb + (size_t)r*768 + kc*96 + c4*4);
        hbf t0 = __float2bfloat16(f.x), t1 = __float2bfloat16(f.y);
        hbf t2 = __float2bfloat16(f.z), t3 = __float2bfloat16(f.w);
        val.x = *(const unsigned short*)&t0; val.y = *(const unsigned short*)&t1;
        val.z = *(const unsigned short*)&t2; val.w = *(const unsigned short*)&t3;
      } else { val.x = 0; val.y = 0; val.z = 0; val.w = 0; }
      *(ushort4*)&Xs[r*104 + c4*4] = val;
    }
    __syncthreads();
#pragma unroll
    for (int kk = 0; kk < 3; ++kk){
      const int ko = kk*32 + (lane>>4)*8;
      bf16x8 a0 = *(const bf16x8*)&Xs[(fr0*16 + l15)*104 + ko];
      bf16x8 a1 = f1 ? *(const bf16x8*)&Xs[(fr1*16 + l15)*104 + ko] : a0;
#pragma unroll
      for (int fc = 0; fc < 13; ++fc){
        bf16x8 bb = *(const bf16x8*)&Xs[(fc*16 + l15)*104 + ko];
        acc0[fc] = __builtin_amdgcn_mfma_f32_16x16x32_bf16(a0, bb, acc0[fc], 0, 0, 0);
        if (f1) acc1[fc] = __builtin_amdgcn_mfma_f32_16x16x32_bf16(a1, bb, acc1[fc], 0, 0, 0);
      }
    }
  }
  const size_t gb = (size_t)b*38416;
  const int cr = (lane>>4)*4;
#pragma unroll
  for (int fc = 0; fc < 13; ++fc){
    const int gc = fc*16 + l15;
    if (gc < 196){
#pragma unroll
      for (int r = 0; r < 4; ++r){
        const int gr = fr0*16 + cr + r;
        if (gr < 196) G[gb + (size_t)gr*196 + gc] = acc0[fc][r];
      }
      if (f1){
#pragma unroll
        for (int r = 0; r < 4; ++r){
          const int gr = fr1*16 + cr + r;
          if (gr < 196) G[gb + (size_t)gr*196 + gc] = acc1[fc][r];
        }
      }
    }
  }
}

// ---------------- eigen: Householder tridiag in LDS + Sturm bisection ----------
// 1024 threads (16 waves), 2 barriers/step. 4 rows/wave x 16 lanes/row:
// one r16 (4 shuffles) reduces FOUR row-dots at once. v,w live in LDS (256
// cols, fully rewritten masked each step); column passes below base>>6 skipped.
__global__ __launch_bounds__(1024) void k_eigen(const float* __restrict__ G, float* __restrict__ scal){
  extern __shared__ float S[];
  float* A   = S;             // 38416 (+80 zeroed pad)
  float* vv  = S + 38496;     // 256
  float* ww  = S + 38752;     // 256
  float* dd  = S + 39008;     // 200
  float* ee  = S + 39208;     // 200
  float* e2  = S + 39408;     // 200
  float* red2= S + 39608;     // 16
  const int n = 196;
  const int tid = threadIdx.x, lane = tid & 63, wave = tid >> 6;
  const int grp = lane >> 4, c16 = lane & 15;
  const int b = blockIdx.x;
  {
    const float4* Gv = (const float4*)(G + (size_t)b*38416);
    float4* Av = (float4*)A;
    for (int u = tid; u < 9604; u += 1024) Av[u] = Gv[u];
    if (tid < 80) S[38416 + tid] = 0.f;
  }
  __syncthreads();
  const int jc = lane << 2;                       // absolute col of comp 0
  for (int k = 0; k <= n-3; ++k){
    const int base = k + 1, m = n - 1 - k;
    const float* rowk = &A[(size_t)k*196];        // pivot row == pivot col (symmetry)
    const float x0 = rowk[base];
    const float4 xv = *(const float4*)(rowk + jc);
    float4 vj;
    vj.x = (jc+0 > base && jc+0 < n) ? xv.x : 0.f;
    vj.y = (jc+1 > base && jc+1 < n) ? xv.y : 0.f;
    vj.z = (jc+2 > base && jc+2 < n) ? xv.z : 0.f;
    vj.w = (jc+3 > base && jc+3 < n) ? xv.w : 0.f;
    float sig = vj.x*vj.x + vj.y*vj.y + vj.z*vj.z + vj.w*vj.w;
    sig = wred(sig);
    float tau = 0.f, v0 = 0.f, alpha = x0;
    if (sig > 1e-20f){
      const float mu = sqrtf(x0*x0 + sig);
      alpha = (x0 > 0.f) ? -mu : mu;
      v0 = x0 - alpha;
      tau = 2.f/(sig + v0*v0);
    }
    if (tid == 0) ee[k] = alpha;
    if (lane == (base >> 2)){
      const int o = base & 3;
      if (o == 0) vj.x = v0; else if (o == 1) vj.y = v0;
      else if (o == 2) vj.z = v0; else vj.w = v0;
    }
    *(float4*)(vv + jc) = vj;                     // all waves write identical data
    const int p0 = base >> 6;
    const int nsw = (m + 63) >> 6;
    // ---- matvec: w_raw = tau * A v ; 4 rows/wave, r16 reduces 4 rows at once ----
    if (tau != 0.f){
      float cpart = 0.f;
      for (int t = 0; t < nsw; ++t){
        const int i = (t << 6) + (wave << 2) + grp;
        float acc = 0.f;
        if (i < m){
          const float* Ar = &A[(size_t)(base+i)*196];
#pragma unroll
          for (int p = 0; p < 4; ++p){
            if (p >= p0){
              const int col = (p << 6) + (c16 << 2);
              const float4 a4 = *(const float4*)(Ar + col);
              const float4 v4 = *(const float4*)(vv + col);
              acc += a4.x*v4.x + a4.y*v4.y + a4.z*v4.z + a4.w*v4.w;
            }
          }
        }
        acc = r16(acc);
        if (i < m && c16 == 0){
          const float wr = tau*acc;
          ww[base+i] = wr;
          cpart += vv[base+i]*wr;
        }
      }
      cpart += __shfl_xor(cpart, 16);
      cpart += __shfl_xor(cpart, 32);
      if (lane == 0) red2[wave] = cpart;
    }
    __syncthreads();                              // B1
    // ---- rank-2 update: A -= v w^T + w v^T, w = w_raw - c2 v ----
    if (tau != 0.f){
      const float4* r2 = (const float4*)red2;
      const float4 q0 = r2[0], q1 = r2[1], q2 = r2[2], q3 = r2[3];
      const float vtw = (q0.x+q0.y+q0.z+q0.w) + (q1.x+q1.y+q1.z+q1.w)
                      + (q2.x+q2.y+q2.z+q2.w) + (q3.x+q3.y+q3.z+q3.w);
      const float c2 = 0.5f*tau*vtw;
      for (int t = 0; t < nsw; ++t){
        const int i = (t << 6) + (wave << 2) + grp;
        if (i < m){
          const float vi = vv[base+i];
          const float wi = ww[base+i] - c2*vi;
          float* Ar = &A[(size_t)(base+i)*196];
#pragma unroll
          for (int p = 0; p < 4; ++p){
            if (p >= p0){
              const int col = (p << 6) + (c16 << 2);
              float4 a4 = *(const float4*)(Ar + col);
              const float4 v4 = *(const float4*)(vv + col);
              float4 w4 = *(const float4*)(ww + col);
              w4.x = (col+0 >= base && col+0 < n) ? (w4.x - c2*v4.x) : 0.f;
              w4.y = (col+1 >= base && col+1 < n) ? (w4.y - c2*v4.y) : 0.f;
              w4.z = (col+2 >= base && col+2 < n) ? (w4.z - c2*v4.z) : 0.f;
              w4.w = (col+3 >= base && col+3 < n) ? (w4.w - c2*v4.w) : 0.f;
              a4.x -= vi*w4.x + wi*v4.x;
              a4.y -= vi*w4.y + wi*v4.y;
              a4.z -= vi*w4.z + wi*v4.z;
              a4.w -= vi*w4.w + wi*v4.w;
              *(float4*)(Ar + col) = a4;
            }
          }
        }
      }
    }
    __syncthreads();                              // B2
  }
  if (tid < n) dd[tid] = A[(size_t)tid*196 + tid];
  if (tid == 0) ee[n-2] = A[(size_t)(n-1)*196 + (n-2)];
  __syncthreads();
  if (tid < n-1) e2[tid] = ee[tid]*ee[tid];
  __syncthreads();
  // Gershgorin bounds
  float lo = 1e30f, hi = -1e30f;
  if (tid < n){
    const float rr = ((tid > 0) ? fabsf(ee[tid-1]) : 0.f) + ((tid < n-1) ? fabsf(ee[tid]) : 0.f);
    lo = dd[tid] - rr; hi = dd[tid] + rr;
  }
  {
    float l2 = lo, h2 = hi;
#pragma unroll
    for (int o = 32; o > 0; o >>= 1){
      l2 = fminf(l2, __shfl_xor(l2, o));
      h2 = fmaxf(h2, __shfl_xor(h2, o));
    }
    if (lane == 0){ ww[wave] = l2; red2[wave] = h2; }
  }
  __syncthreads();
  float glo = ww[0], ghi = red2[0];
#pragma unroll
  for (int w2 = 1; w2 < 16; ++w2){ glo = fminf(glo, ww[w2]); ghi = fmaxf(ghi, red2[w2]); }
  __syncthreads();
  // Sturm bisection: thread tid finds the tid-th smallest eigenvalue
  float sv = 0.f;
  if (tid < n){
    float lob = glo, hib = ghi;
    for (int it2 = 0; it2 < 26; ++it2){
      const float mid = 0.5f*(lob + hib);
      float q = dd[0] - mid;
      int cnt = (q < 0.f) ? 1 : 0;
      for (int i = 1; i < n; ++i){
        const float r = fast_rcp(q);
        q = (dd[i] - mid) - e2[i-1]*r;
        q = (fabsf(q) < 1e-6f) ? -1e-6f : q;
        cnt += (q < 0.f) ? 1 : 0;
      }
      if (cnt <= tid) lob = mid; else hib = mid;
    }
    sv = sqrtf(fmaxf(0.5f*(lob + hib), 0.f));
  }
  __syncthreads();
  if (tid < n) ww[tid] = sv;
  __syncthreads();
  if (tid == 0){
    float tot = 0.f;
    for (int i = 0; i < n; ++i) tot += ww[i];
    const float thr = 0.99f*tot;
    float cs = 0.f; int rank = 0;
    for (int i = n-1; i >= 0; --i){ cs += ww[i]; rank += (cs <= thr) ? 1 : 0; }
    atomicAdd(&scal[1], (float)rank);
  }
}

// ---------------- transpose + f32->bf16 for weights ----------------------------
__global__ __launch_bounds__(256) void k_tr(const float* __restrict__ in, hbf* __restrict__ outp,
                                            int Rr, int Cc){
  __shared__ float t[32][33];
  const int tid = threadIdx.x;
  const int lc = tid & 31, lr = tid >> 5;
  const int c0 = blockIdx.x*32, r0 = blockIdx.y*32;
#pragma unroll
  for (int i = 0; i < 4; ++i)
    t[lr + i*8][lc] = in[(size_t)(r0 + lr + i*8)*Cc + c0 + lc];
  __syncthreads();
#pragma unroll
  for (int i = 0; i < 4; ++i)
    outp[(size_t)(c0 + lr + i*8)*Rr + r0 + lc] = __float2bfloat16(t[lc][lr + i*8]);
}

// ---------------- GEMM: A[M,K] * B^T[N,K], bf16 MFMA 16x16x32, 64x64 tiles ------
template<int EPI>
__global__ __launch_bounds__(256) void k_gemm(const hbf* __restrict__ Aa, const hbf* __restrict__ Bb,
    const float* __restrict__ bias, void* __restrict__ outp, int Mi, int Ni, int Ki){
  __shared__ hbf As[64*72];
  __shared__ hbf Bs[64*72];
  const int tid = threadIdx.x, lane = tid & 63, wave = tid >> 6;
  const int row0 = blockIdx.y*64, col0 = blockIdx.x*64;
  const int m0 = (wave >> 1)*32, n0 = (wave & 1)*32;
  const int l15 = lane & 15, lk = (lane >> 4)*8;
  const int sr = tid >> 3, sc = (tid & 7)*8;
  f32x4 acc00 = {}, acc01 = {}, acc10 = {}, acc11 = {};
  for (int kt = 0; kt < Ki; kt += 64){
    __syncthreads();
    *(uint4*)&As[sr*72 + sc]        = *(const uint4*)&Aa[(size_t)(row0+sr)*Ki + kt + sc];
    *(uint4*)&As[(sr+32)*72 + sc]   = *(const uint4*)&Aa[(size_t)(row0+sr+32)*Ki + kt + sc];
    *(uint4*)&Bs[sr*72 + sc]        = *(const uint4*)&Bb[(size_t)(col0+sr)*Ki + kt + sc];
    *(uint4*)&Bs[(sr+32)*72 + sc]   = *(const uint4*)&Bb[(size_t)(col0+sr+32)*Ki + kt + sc];
    __syncthreads();
#pragma unroll
    for (int kk = 0; kk < 2; ++kk){
      const int ko = kk*32 + lk;
      bf16x8 a0 = *(const bf16x8*)&As[(m0 + l15)*72 + ko];
      bf16x8 a1 = *(const bf16x8*)&As[(m0 + 16 + l15)*72 + ko];
      bf16x8 b0 = *(const bf16x8*)&Bs[(n0 + l15)*72 + ko];
      bf16x8 b1 = *(const bf16x8*)&Bs[(n0 + 16 + l15)*72 + ko];
      acc00 = __builtin_amdgcn_mfma_f32_16x16x32_bf16(a0, b0, acc00, 0, 0, 0);
      acc01 = __builtin_amdgcn_mfma_f32_16x16x32_bf16(a0, b1, acc01, 0, 0, 0);
      acc10 = __builtin_amdgcn_mfma_f32_16x16x32_bf16(a1, b0, acc10, 0, 0, 0);
      acc11 = __builtin_amdgcn_mfma_f32_16x16x32_bf16(a1, b1, acc11, 0, 0, 0);
    }
  }
  const int cr = (lane >> 4)*4;
#pragma unroll
  for (int i = 0; i < 2; ++i){
#pragma unroll
    for (int j = 0; j < 2; ++j){
      f32x4 av = (i == 0) ? ((j == 0) ? acc00 : acc01) : ((j == 0) ? acc10 : acc11);
      const int gcol = col0 + n0 + j*16 + l15;
#pragma unroll
      for (int r = 0; r < 4; ++r){
        const int grow = row0 + m0 + i*16 + cr + r;
        float v = av[r];
        if (EPI == 1){
          v += bias[gcol];
          v = 0.5f*v*(1.f + erff(v*0.70710678118654752f));
          ((hbf*)outp)[(size_t)grow*Ni + gcol] = __float2bfloat16(v);
        } else if (EPI == 2){
          v += bias[gcol];
          ((float*)outp)[(size_t)grow*Ni + gcol] = v;
        } else {
          ((float*)outp)[(size_t)grow*Ni + gcol] = v;
        }
      }
    }
  }
}

// ---------------- LayerNorm over 768, one wave per row --------------------------
__global__ __launch_bounds__(256) void k_ln(const float* __restrict__ h, const float* __restrict__ gam,
    const float* __restrict__ bet, hbf* __restrict__ hn){
  const int tid = threadIdx.x, lane = tid & 63, wave = tid >> 6;
  const int row = blockIdx.x*4 + wave;
  const float* hr = h + (size_t)row*768;
  const int off = lane*4;
  float4 v0 = *(const float4*)(hr + off);
  float4 v1 = *(const float4*)(hr + 256 + off);
  float4 v2 = *(const float4*)(hr + 512 + off);
  float s = v0.x+v0.y+v0.z+v0.w + v1.x+v1.y+v1.z+v1.w + v2.x+v2.y+v2.z+v2.w;
  s = wred(s);
  const float mu = s*(1.f/768.f);
  float q = 0.f;
  q += (v0.x-mu)*(v0.x-mu); q += (v0.y-mu)*(v0.y-mu); q += (v0.z-mu)*(v0.z-mu); q += (v0.w-mu)*(v0.w-mu);
  q += (v1.x-mu)*(v1.x-mu); q += (v1.y-mu)*(v1.y-mu); q += (v1.z-mu)*(v1.z-mu); q += (v1.w-mu)*(v1.w-mu);
  q += (v2.x-mu)*(v2.x-mu); q += (v2.y-mu)*(v2.y-mu); q += (v2.z-mu)*(v2.z-mu); q += (v2.w-mu)*(v2.w-mu);
  q = wred(q);
  const float rs = 1.f/sqrtf(q*(1.f/768.f) + 1e-5f);
  float4 g0 = *(const float4*)(gam + off), g1 = *(const float4*)(gam + 256 + off), g2 = *(const float4*)(gam + 512 + off);
  float4 t0 = *(const float4*)(bet + off), t1 = *(const float4*)(bet + 256 + off), t2 = *(const float4*)(bet + 512 + off);
  hbf* o = hn + (size_t)row*768;
  o[off+0] = __float2bfloat16((v0.x-mu)*rs*g0.x + t0.x);
  o[off+1] = __float2bfloat16((v0.y-mu)*rs*g0.y + t0.y);
  o[off+2] = __float2bfloat16((v0.z-mu)*rs*g0.z + t0.z);
  o[off+3] = __float2bfloat16((v0.w-mu)*rs*g0.w + t0.w);
  o[256+off+0] = __float2bfloat16((v1.x-mu)*rs*g1.x + t1.x);
  o[256+off+1] = __float2bfloat16((v1.y-mu)*rs*g1.y + t1.y);
  o[256+off+2] = __float2bfloat16((v1.z-mu)*rs*g1.z + t1.z);
  o[256+off+3] = __float2bfloat16((v1.w-mu)*rs*g1.w + t1.w);
  o[512+off+0] = __float2bfloat16((v2.x-mu)*rs*g2.x + t2.x);
  o[512+off+1] = __float2bfloat16((v2.y-mu)*rs*g2.y + t2.y);
  o[512+off+2] = __float2bfloat16((v2.z-mu)*rs*g2.z + t2.z);
  o[512+off+3] = __float2bfloat16((v2.w-mu)*rs*g2.w + t2.w);
}

// ---------------- head: normalize tok, grouped cosine logits, cls ---------------
__global__ __launch_bounds__(256) void k_head(const float* __restrict__ tok, const float* __restrict__ ce,
    const float* __restrict__ clsW, const float* __restrict__ clsb, const float* __restrict__ lgs,
    float* __restrict__ out){
  __shared__ float tkn[7*512];
  __shared__ float il[40];
  const int tid = threadIdx.x, lane = tid & 63, wave = tid >> 6;
  const int b = blockIdx.x;
  const float ls = lgs[0];
  for (int g = wave; g < 7; g += 4){
    const float* tr = tok + (size_t)(b*7 + g)*512;
    float4 u0 = *(const float4*)(tr + (lane<<3));
    float4 u1 = *(const float4*)(tr + (lane<<3) + 4);
    float s = d4(u0,u0) + d4(u1,u1);
    s = wred(s);
    const float inv = 1.f/sqrtf(s);
    float* dst = &tkn[g*512 + (lane<<3)];
    dst[0] = u0.x*inv; dst[1] = u0.y*inv; dst[2] = u0.z*inv; dst[3] = u0.w*inv;
    dst[4] = u1.x*inv; dst[5] = u1.y*inv; dst[6] = u1.z*inv; dst[7] = u1.w*inv;
  }
  __syncthreads();
  for (int c = wave; c < 34; c += 4){
    const int g = (c < 30) ? (c/5) : 6;
    const float* tp = &tkn[g*512 + (lane<<3)];
    const float* cp = ce + (size_t)c*512 + (lane<<3);
    float s = tp[0]*cp[0] + tp[1]*cp[1] + tp[2]*cp[2] + tp[3]*cp[3]
            + tp[4]*cp[4] + tp[5]*cp[5] + tp[6]*cp[6] + tp[7]*cp[7];
    s = wred(s);
    if (lane == 0){
      const float v = ls*s;
      il[c] = v;
      out[1792 + b*34 + c] = v;
    }
  }
  __syncthreads();
  if (tid < 7){
    float s = clsb[tid];
    for (int c = 0; c < 34; ++c) s += il[c]*clsW[c*7 + tid];
    out[b*7 + tid] = s;
  }
}

// ---------------- finalize scalars ----------------------------------------------
__global__ void k_fin(const float* __restrict__ scal, float* __restrict__ out){
  if (threadIdx.x == 0){
    out[10496] = 2.f*scal[0]/(float)(256*196*768);
    out[10497] = scal[1]*(1.f/256.f);
  }
}

extern "C" void kernel_launch(void* const* d_in, const int* in_sizes, int n_in,
                              void* d_out, int out_size, void* d_ws, size_t ws_size,
                              hipStream_t stream) {
  (void)in_sizes; (void)n_in; (void)out_size; (void)ws_size;
  const float* x    = (const float*)d_in[0];
  const float* vqcb = (const float*)d_in[1];
  const float* agcb = (const float*)d_in[2];
  const float* W1   = (const float*)d_in[3];
  const float* b1   = (const float*)d_in[4];
  const float* W2   = (const float*)d_in[5];
  const float* b2   = (const float*)d_in[6];
  const float* gam  = (const float*)d_in[7];
  const float* bet  = (const float*)d_in[8];
  const float* Wp   = (const float*)d_in[9];
  const float* ce   = (const float*)d_in[10];
  const float* clsW = (const float*)d_in[11];
  const float* clsb = (const float*)d_in[12];
  const float* lgs  = (const float*)d_in[13];
  float* out = (float*)d_out;
  char* w = (char*)d_ws;

  // workspace layout (~50 MB): scalars | G (reused later for MLP temps) | aggbf | W1t | W2t | Wpt
  float* scal  = (float*)w;
  float* G     = (float*)(w + 256);
  hbf*   aggbf = (hbf*)(w + 39338240ULL);
  hbf*   W1t   = (hbf*)(w + 42090752ULL);
  hbf*   W2t   = (hbf*)(w + 46809344ULL);
  hbf*   Wpt   = (hbf*)(w + 51527936ULL);
  // reuse of G region (G is dead after k_eigen; all consumers run after it):
  hbf*   h1    = (hbf*)(w + 256);
  float* hbuf  = (float*)(w + 256 + 16777216ULL);
  hbf*   hn    = (hbf*)(w + 256 + 25165824ULL);
  float* tok   = (float*)(w + 256 + 29360128ULL);

  k_init<<<dim3(1), dim3(64), 0, stream>>>(scal);
  k_dist<<<dim3(256), dim3(512), 0, stream>>>(x, vqcb, agcb, aggbf, scal);
  k_gram<<<dim3(256), dim3(512), 0, stream>>>(x, G);
  const int EIG_SMEM = 39624*4; // 158,496 B
  hipFuncSetAttribute((const void*)k_eigen, hipFuncAttributeMaxDynamicSharedMemorySize, EIG_SMEM);
  k_eigen<<<dim3(256), dim3(1024), EIG_SMEM, stream>>>(G, scal);
  k_tr<<<dim3(96,24), dim3(256), 0, stream>>>(W1, W1t, 768, 3072);
  k_tr<<<dim3(24,96), dim3(256), 0, stream>>>(W2, W2t, 3072, 768);
  k_tr<<<dim3(16,24), dim3(256), 0, stream>>>(Wp, Wpt, 768, 512);
  k_gemm<1><<<dim3(48,28), dim3(256), 0, stream>>>(aggbf, W1t, b1, (void*)h1, 1792, 3072, 768);
  k_gemm<2><<<dim3(12,28), dim3(256), 0, stream>>>(h1, W2t, b2, (void*)hbuf, 1792, 768, 3072);
  k_ln<<<dim3(448), dim3(256), 0, stream>>>(hbuf, gam, bet, hn);
  k_gemm<3><<<dim3(8,28), dim3(256), 0, stream>>>(hn, Wpt, nullptr, (void*)tok, 1792, 512, 768);
  k_head<<<dim3(256), dim3(256), 0, stream>>>(tok, ce, clsW, clsb, lgs, out);
  k_fin<<<dim3(1), dim3(64), 0, stream>>>(scal, out);
}

// Round 7
// 1114.172 us; speedup vs baseline: 1.7142x; 1.0422x over previous
//
#include <hip/hip_runtime.h>
#include <hip/hip_bf16.h>
#include <math.h>

using hbf = __hip_bfloat16;
typedef __bf16 bf16x8 __attribute__((ext_vector_type(8)));
typedef float f32x4 __attribute__((ext_vector_type(4)));

__device__ inline float wred(float v){
#pragma unroll
  for (int o = 32; o > 0; o >>= 1) v += __shfl_xor(v, o);
  return v;
}
__device__ inline float r16(float v){
  v += __shfl_xor(v, 1); v += __shfl_xor(v, 2);
  v += __shfl_xor(v, 4); v += __shfl_xor(v, 8);
  return v;
}
__device__ inline float fast_rcp(float x){
  float r; asm("v_rcp_f32 %0, %1" : "=v"(r) : "v"(x)); return r;
}
__device__ inline float d4(const float4& a, const float4& b){
  return a.x*b.x + a.y*b.y + a.z*b.z + a.w*b.w;
}

// ---------------- init: zero the two accumulators (ws is poisoned 0xAA once) ----
__global__ void k_init(float* scal){
  if (threadIdx.x < 2) scal[threadIdx.x] = 0.f;
}

// ---------------- fused distances / softmax / agg / vq loss --------------------
// one block per batch; 8 waves; wave w handles tokens n = it*8 + w
__global__ __launch_bounds__(512) void k_dist(const float* __restrict__ x,
    const float* __restrict__ vqcb, const float* __restrict__ agcb,
    hbf* __restrict__ aggbf, float* __restrict__ scal){
  __shared__ float cA[5376];
  __shared__ float cV[5376];
  __shared__ float sqA[7], sqV[7];
  const int tid = threadIdx.x, lane = tid & 63, wave = tid >> 6;
  const int b = blockIdx.x;
  for (int i = tid; i < 5376; i += 512){ cA[i] = agcb[i]; cV[i] = vqcb[i]; }
  __syncthreads();
  {
    int grp = tid >> 4, l16 = tid & 15;
    if (grp < 14){
      const float* s = (grp < 7) ? &cA[grp*768] : &cV[(grp-7)*768];
      float acc = 0.f;
      for (int j = l16; j < 768; j += 16) acc += s[j]*s[j];
      acc = r16(acc);
      if (l16 == 0){ if (grp < 7) sqA[grp] = acc; else sqV[grp-7] = acc; }
    }
  }
  __syncthreads();
  float sqAr[7], sqVr[7];
#pragma unroll
  for (int k = 0; k < 7; ++k){ sqAr[k] = sqA[k]; sqVr[k] = sqV[k]; }

  float4 aR[7][3];
#pragma unroll
  for (int k = 0; k < 7; ++k)
#pragma unroll
    for (int c = 0; c < 3; ++c) aR[k][c] = make_float4(0.f,0.f,0.f,0.f);
  float loss = 0.f;

  const float* xb = x + (size_t)b*196*768;
  float4 cx0, cx1, cx2, nx0, nx1, nx2;
  { const float* p = xb + (size_t)wave*768 + (lane<<2);
    cx0 = *(const float4*)(p); cx1 = *(const float4*)(p+256); cx2 = *(const float4*)(p+512); }
  for (int it = 0; it < 25; ++it){
    const int n = it*8 + wave;
    const int nn = n + 8;
    if (nn < 196){
      const float* p = xb + (size_t)nn*768 + (lane<<2);
      nx0 = *(const float4*)(p); nx1 = *(const float4*)(p+256); nx2 = *(const float4*)(p+512);
    }
    if (n < 196){
      float xsq = d4(cx0,cx0)+d4(cx1,cx1)+d4(cx2,cx2);
      float dA[7], dV[7];
#pragma unroll
      for (int k = 0; k < 7; ++k){
        const float4* pa = (const float4*)&cA[k*768];
        const float4* pv = (const float4*)&cV[k*768];
        float4 a0 = pa[lane], a1 = pa[64+lane], a2 = pa[128+lane];
        float4 q0 = pv[lane], q1 = pv[64+lane], q2 = pv[128+lane];
        dA[k] = d4(cx0,a0)+d4(cx1,a1)+d4(cx2,a2);
        dV[k] = d4(cx0,q0)+d4(cx1,q1)+d4(cx2,q2);
      }
      xsq = wred(xsq);
#pragma unroll
      for (int k = 0; k < 7; ++k){ dA[k] = wred(dA[k]); dV[k] = wred(dV[k]); }
      float lg[7], mx = -1e30f;
#pragma unroll
      for (int k = 0; k < 7; ++k){ lg[k] = 2.f*dA[k] - sqAr[k]; mx = fmaxf(mx, lg[k]); }
      float pr[7], ssum = 0.f;
#pragma unroll
      for (int k = 0; k < 7; ++k){ pr[k] = expf(lg[k]-mx); ssum += pr[k]; }
      const float inv = 1.f/ssum;
      float mn = 1e30f;
#pragma unroll
      for (int k = 0; k < 7; ++k) mn = fminf(mn, sqVr[k] - 2.f*dV[k]);
      loss += xsq + mn;
#pragma unroll
      for (int k = 0; k < 7; ++k){
        const float w = pr[k]*inv;
        aR[k][0].x += w*cx0.x; aR[k][0].y += w*cx0.y; aR[k][0].z += w*cx0.z; aR[k][0].w += w*cx0.w;
        aR[k][1].x += w*cx1.x; aR[k][1].y += w*cx1.y; aR[k][1].z += w*cx1.z; aR[k][1].w += w*cx1.w;
        aR[k][2].x += w*cx2.x; aR[k][2].y += w*cx2.y; aR[k][2].z += w*cx2.z; aR[k][2].w += w*cx2.w;
      }
    }
    cx0 = nx0; cx1 = nx1; cx2 = nx2;
  }
  __syncthreads();
  for (int i = tid; i < 5376; i += 512) cA[i] = 0.f;
  __syncthreads();
  for (int w = 0; w < 8; ++w){
    if (wave == w){
#pragma unroll
      for (int k = 0; k < 7; ++k)
#pragma unroll
        for (int c = 0; c < 3; ++c){
          float* p = &cA[k*768 + c*256 + (lane<<2)];
          p[0] += aR[k][c].x; p[1] += aR[k][c].y; p[2] += aR[k][c].z; p[3] += aR[k][c].w;
        }
    }
    __syncthreads();
  }
  for (int i = tid; i < 5376; i += 512) aggbf[(size_t)b*5376 + i] = __float2bfloat16(cA[i]);
  if (lane == 0) atomicAdd(&scal[0], loss);
}

// ---------------- Gram: G = X Xtr per batch, bf16 MFMA, X staged in LDS --------
__global__ __launch_bounds__(512) void k_gram(const float* __restrict__ x, float* __restrict__ G){
  __shared__ hbf Xs[208*104];
  const int tid = threadIdx.x, lane = tid & 63, wave = tid >> 6;
  const int b = blockIdx.x;
  const int l15 = lane & 15;
  const int fr0 = wave, fr1 = wave + 8;
  const bool f1 = (fr1 < 13);
  f32x4 acc0[13] = {};
  f32x4 acc1[13] = {};
  const float* xb = x + (size_t)b*196*768;
  for (int kc = 0; kc < 8; ++kc){
    __syncthreads();
    for (int u = tid; u < 4992; u += 512){
      const int r = u / 24, c4 = u - r*24;
      ushort4 val;
      if (r < 196){
        float4 f = *(const float4*)(xb + (size_t)r*768 + kc*96 + c4*4);
        hbf t0 = __float2bfloat16(f.x), t1 = __float2bfloat16(f.y);
        hbf t2 = __float2bfloat16(f.z), t3 = __float2bfloat16(f.w);
        val.x = *(const unsigned short*)&t0; val.y = *(const unsigned short*)&t1;
        val.z = *(const unsigned short*)&t2; val.w = *(const unsigned short*)&t3;
      } else { val.x = 0; val.y = 0; val.z = 0; val.w = 0; }
      *(ushort4*)&Xs[r*104 + c4*4] = val;
    }
    __syncthreads();
#pragma unroll
    for (int kk = 0; kk < 3; ++kk){
      const int ko = kk*32 + (lane>>4)*8;
      bf16x8 a0 = *(const bf16x8*)&Xs[(fr0*16 + l15)*104 + ko];
      bf16x8 a1 = f1 ? *(const bf16x8*)&Xs[(fr1*16 + l15)*104 + ko] : a0;
#pragma unroll
      for (int fc = 0; fc < 13; ++fc){
        bf16x8 bb = *(const bf16x8*)&Xs[(fc*16 + l15)*104 + ko];
        acc0[fc] = __builtin_amdgcn_mfma_f32_16x16x32_bf16(a0, bb, acc0[fc], 0, 0, 0);
        if (f1) acc1[fc] = __builtin_amdgcn_mfma_f32_16x16x32_bf16(a1, bb, acc1[fc], 0, 0, 0);
      }
    }
  }
  const size_t gb = (size_t)b*38416;
  const int cr = (lane>>4)*4;
#pragma unroll
  for (int fc = 0; fc < 13; ++fc){
    const int gc = fc*16 + l15;
    if (gc < 196){
#pragma unroll
      for (int r = 0; r < 4; ++r){
        const int gr = fr0*16 + cr + r;
        if (gr < 196) G[gb + (size_t)gr*196 + gc] = acc0[fc][r];
      }
      if (f1){
#pragma unroll
        for (int r = 0; r < 4; ++r){
          const int gr = fr1*16 + cr + r;
          if (gr < 196) G[gb + (size_t)gr*196 + gc] = acc1[fc][r];
        }
      }
    }
  }
}

// ---------------- eigen: Householder tridiag in LDS + Sturm bisection ----------
// 1024 threads (16 waves), 2 barriers/step, 4 rows/wave x 16 lanes/row.
// v and w are hoisted into per-lane registers once per step (statically
// unrolled col passes); inner loops are pure {ds_read_b128, fma, ds_write}.
__global__ __launch_bounds__(1024) void k_eigen(const float* __restrict__ G, float* __restrict__ scal){
  extern __shared__ float S[];
  float* A   = S;             // 38416 (+80 zeroed pad: row-195 b128 tail spill)
  float* ww  = S + 38496;     // 256
  float* dd  = S + 38752;     // 200
  float* ee  = S + 38952;     // 200
  float* e2  = S + 39152;     // 200
  float* red2= S + 39352;     // 16 (16B-aligned)
  const int n = 196;
  const int tid = threadIdx.x, lane = tid & 63, wave = tid >> 6;
  const int grp = lane >> 4, c16 = lane & 15;
  const int b = blockIdx.x;
  {
    const float4* Gv = (const float4*)(G + (size_t)b*38416);
    float4* Av = (float4*)A;
    for (int u = tid; u < 9604; u += 1024) Av[u] = Gv[u];
    if (tid < 80) S[38416 + tid] = 0.f;
  }
  __syncthreads();
  for (int k = 0; k <= n-3; ++k){
    const int base = k + 1, m = n - 1 - k;
    const float* rowk = &A[(size_t)k*196];        // pivot row == pivot col (symmetry)
    const float x0 = rowk[base];
    // ---- hoist masked v into 4 per-lane register float4s; sig via one r16 ----
    float4 v4[4];
    float sig = 0.f;
#pragma unroll
    for (int p = 0; p < 4; ++p){
      const int col = (p << 6) + (c16 << 2);
      float4 xv = *(const float4*)(rowk + col);
      xv.x = (col+0 > base && col+0 < n) ? xv.x : 0.f;
      xv.y = (col+1 > base && col+1 < n) ? xv.y : 0.f;
      xv.z = (col+2 > base && col+2 < n) ? xv.z : 0.f;
      xv.w = (col+3 > base && col+3 < n) ? xv.w : 0.f;
      v4[p] = xv;
      sig += xv.x*xv.x + xv.y*xv.y + xv.z*xv.z + xv.w*xv.w;
    }
    sig = r16(sig);                               // each 16-lane grp holds full sum
    float tau = 0.f, v0 = 0.f, alpha = x0;
    if (sig > 1e-20f){
      const float mu = sqrtf(x0*x0 + sig);
      alpha = (x0 > 0.f) ? -mu : mu;
      v0 = x0 - alpha;
      tau = 2.f/(sig + v0*v0);
    }
    if (tid == 0) ee[k] = alpha;
    // fold v0 into the base component (static v4 indexing preserved)
#pragma unroll
    for (int p = 0; p < 4; ++p){
      const int col = (p << 6) + (c16 << 2);
      v4[p].x = (col+0 == base) ? v0 : v4[p].x;
      v4[p].y = (col+1 == base) ? v0 : v4[p].y;
      v4[p].z = (col+2 == base) ? v0 : v4[p].z;
      v4[p].w = (col+3 == base) ? v0 : v4[p].w;
    }
    const int p0 = base >> 6;
    const int nsw = (m + 63) >> 6;
    // ---- matvec: w_raw = tau * A v ; 4 rows/wave, one r16 per 4 rows ----
    if (tau != 0.f){
      float cpart = 0.f;
      for (int t = 0; t < nsw; ++t){
        const int i = (t << 6) + (wave << 2) + grp;
        float acc = 0.f;
        if (i < m){
          const float* Ar = &A[(size_t)(base+i)*196];
#pragma unroll
          for (int p = 0; p < 4; ++p){
            if (p >= p0){
              const int col = (p << 6) + (c16 << 2);
              const float4 a4 = *(const float4*)(Ar + col);
              acc += a4.x*v4[p].x + a4.y*v4[p].y + a4.z*v4[p].z + a4.w*v4[p].w;
            }
          }
        }
        acc = r16(acc);
        if (i < m && c16 == 0){
          const float wr = tau*acc;
          ww[base+i] = wr;
          cpart += ((i == 0) ? v0 : rowk[base+i])*wr;
        }
      }
      cpart += __shfl_xor(cpart, 16);
      cpart += __shfl_xor(cpart, 32);
      if (lane == 0) red2[wave] = cpart;
    }
    __syncthreads();                              // B1
    // ---- rank-2 update: A -= v w^T + w v^T, w = w_raw - c2 v (w hoisted) ----
    if (tau != 0.f){
      const float4* r2 = (const float4*)red2;
      const float4 q0 = r2[0], q1 = r2[1], q2 = r2[2], q3 = r2[3];
      const float vtw = (q0.x+q0.y+q0.z+q0.w) + (q1.x+q1.y+q1.z+q1.w)
                      + (q2.x+q2.y+q2.z+q2.w) + (q3.x+q3.y+q3.z+q3.w);
      const float c2 = 0.5f*tau*vtw;
      float4 w4[4];
#pragma unroll
      for (int p = 0; p < 4; ++p){
        const int col = (p << 6) + (c16 << 2);
        const float4 t4 = *(const float4*)(ww + col);
        w4[p].x = (col+0 >= base && col+0 < n) ? (t4.x - c2*v4[p].x) : 0.f;
        w4[p].y = (col+1 >= base && col+1 < n) ? (t4.y - c2*v4[p].y) : 0.f;
        w4[p].z = (col+2 >= base && col+2 < n) ? (t4.z - c2*v4[p].z) : 0.f;
        w4[p].w = (col+3 >= base && col+3 < n) ? (t4.w - c2*v4[p].w) : 0.f;
      }
      for (int t = 0; t < nsw; ++t){
        const int i = (t << 6) + (wave << 2) + grp;
        if (i < m){
          const float vi = (i == 0) ? v0 : rowk[base+i];   // broadcast reads
          const float wi = ww[base+i] - c2*vi;
          float* Ar = &A[(size_t)(base+i)*196];
#pragma unroll
          for (int p = 0; p < 4; ++p){
            if (p >= p0){
              const int col = (p << 6) + (c16 << 2);
              float4 a4 = *(const float4*)(Ar + col);
              a4.x -= vi*w4[p].x + wi*v4[p].x;
              a4.y -= vi*w4[p].y + wi*v4[p].y;
              a4.z -= vi*w4[p].z + wi*v4[p].z;
              a4.w -= vi*w4[p].w + wi*v4[p].w;
              *(float4*)(Ar + col) = a4;
            }
          }
        }
      }
    }
    __syncthreads();                              // B2
  }
  if (tid < n) dd[tid] = A[(size_t)tid*196 + tid];
  if (tid == 0) ee[n-2] = A[(size_t)(n-1)*196 + (n-2)];
  __syncthreads();
  if (tid < n-1) e2[tid] = ee[tid]*ee[tid];
  __syncthreads();
  // Gershgorin bounds
  float lo = 1e30f, hi = -1e30f;
  if (tid < n){
    const float rr = ((tid > 0) ? fabsf(ee[tid-1]) : 0.f) + ((tid < n-1) ? fabsf(ee[tid]) : 0.f);
    lo = dd[tid] - rr; hi = dd[tid] + rr;
  }
  {
    float l2 = lo, h2 = hi;
#pragma unroll
    for (int o = 32; o > 0; o >>= 1){
      l2 = fminf(l2, __shfl_xor(l2, o));
      h2 = fmaxf(h2, __shfl_xor(h2, o));
    }
    if (lane == 0){ ww[wave] = l2; red2[wave] = h2; }
  }
  __syncthreads();
  float glo = ww[0], ghi = red2[0];
#pragma unroll
  for (int w2 = 1; w2 < 16; ++w2){ glo = fminf(glo, ww[w2]); ghi = fmaxf(ghi, red2[w2]); }
  __syncthreads();
  // Sturm bisection: thread tid finds the tid-th smallest eigenvalue
  float sv = 0.f;
  if (tid < n){
    float lob = glo, hib = ghi;
    for (int it2 = 0; it2 < 26; ++it2){
      const float mid = 0.5f*(lob + hib);
      float q = dd[0] - mid;
      int cnt = (q < 0.f) ? 1 : 0;
      for (int i = 1; i < n; ++i){
        const float r = fast_rcp(q);
        q = (dd[i] - mid) - e2[i-1]*r;
        q = (fabsf(q) < 1e-6f) ? -1e-6f : q;
        cnt += (q < 0.f) ? 1 : 0;
      }
      if (cnt <= tid) lob = mid; else hib = mid;
    }
    sv = sqrtf(fmaxf(0.5f*(lob + hib), 0.f));
  }
  __syncthreads();
  if (tid < n) ww[tid] = sv;
  __syncthreads();
  if (tid == 0){
    float tot = 0.f;
    for (int i = 0; i < n; ++i) tot += ww[i];
    const float thr = 0.99f*tot;
    float cs = 0.f; int rank = 0;
    for (int i = n-1; i >= 0; --i){ cs += ww[i]; rank += (cs <= thr) ? 1 : 0; }
    atomicAdd(&scal[1], (float)rank);
  }
}

// ---------------- transpose + f32->bf16 for weights ----------------------------
__global__ __launch_bounds__(256) void k_tr(const float* __restrict__ in, hbf* __restrict__ outp,
                                            int Rr, int Cc){
  __shared__ float t[32][33];
  const int tid = threadIdx.x;
  const int lc = tid & 31, lr = tid >> 5;
  const int c0 = blockIdx.x*32, r0 = blockIdx.y*32;
#pragma unroll
  for (int i = 0; i < 4; ++i)
    t[lr + i*8][lc] = in[(size_t)(r0 + lr + i*8)*Cc + c0 + lc];
  __syncthreads();
#pragma unroll
  for (int i = 0; i < 4; ++i)
    outp[(size_t)(c0 + lr + i*8)*Rr + r0 + lc] = __float2bfloat16(t[lc][lr + i*8]);
}

// ---------------- GEMM: A[M,K] * B^T[N,K], bf16 MFMA 16x16x32, 64x64 tiles ------
template<int EPI>
__global__ __launch_bounds__(256) void k_gemm(const hbf* __restrict__ Aa, const hbf* __restrict__ Bb,
    const float* __restrict__ bias, void* __restrict__ outp, int Mi, int Ni, int Ki){
  __shared__ hbf As[64*72];
  __shared__ hbf Bs[64*72];
  const int tid = threadIdx.x, lane = tid & 63, wave = tid >> 6;
  const int row0 = blockIdx.y*64, col0 = blockIdx.x*64;
  const int m0 = (wave >> 1)*32, n0 = (wave & 1)*32;
  const int l15 = lane & 15, lk = (lane >> 4)*8;
  const int sr = tid >> 3, sc = (tid & 7)*8;
  f32x4 acc00 = {}, acc01 = {}, acc10 = {}, acc11 = {};
  for (int kt = 0; kt < Ki; kt += 64){
    __syncthreads();
    *(uint4*)&As[sr*72 + sc]        = *(const uint4*)&Aa[(size_t)(row0+sr)*Ki + kt + sc];
    *(uint4*)&As[(sr+32)*72 + sc]   = *(const uint4*)&Aa[(size_t)(row0+sr+32)*Ki + kt + sc];
    *(uint4*)&Bs[sr*72 + sc]        = *(const uint4*)&Bb[(size_t)(col0+sr)*Ki + kt + sc];
    *(uint4*)&Bs[(sr+32)*72 + sc]   = *(const uint4*)&Bb[(size_t)(col0+sr+32)*Ki + kt + sc];
    __syncthreads();
#pragma unroll
    for (int kk = 0; kk < 2; ++kk){
      const int ko = kk*32 + lk;
      bf16x8 a0 = *(const bf16x8*)&As[(m0 + l15)*72 + ko];
      bf16x8 a1 = *(const bf16x8*)&As[(m0 + 16 + l15)*72 + ko];
      bf16x8 b0 = *(const bf16x8*)&Bs[(n0 + l15)*72 + ko];
      bf16x8 b1 = *(const bf16x8*)&Bs[(n0 + 16 + l15)*72 + ko];
      acc00 = __builtin_amdgcn_mfma_f32_16x16x32_bf16(a0, b0, acc00, 0, 0, 0);
      acc01 = __builtin_amdgcn_mfma_f32_16x16x32_bf16(a0, b1, acc01, 0, 0, 0);
      acc10 = __builtin_amdgcn_mfma_f32_16x16x32_bf16(a1, b0, acc10, 0, 0, 0);
      acc11 = __builtin_amdgcn_mfma_f32_16x16x32_bf16(a1, b1, acc11, 0, 0, 0);
    }
  }
  const int cr = (lane >> 4)*4;
#pragma unroll
  for (int i = 0; i < 2; ++i){
#pragma unroll
    for (int j = 0; j < 2; ++j){
      f32x4 av = (i == 0) ? ((j == 0) ? acc00 : acc01) : ((j == 0) ? acc10 : acc11);
      const int gcol = col0 + n0 + j*16 + l15;
#pragma unroll
      for (int r = 0; r < 4; ++r){
        const int grow = row0 + m0 + i*16 + cr + r;
        float v = av[r];
        if (EPI == 1){
          v += bias[gcol];
          v = 0.5f*v*(1.f + erff(v*0.70710678118654752f));
          ((hbf*)outp)[(size_t)grow*Ni + gcol] = __float2bfloat16(v);
        } else if (EPI == 2){
          v += bias[gcol];
          ((float*)outp)[(size_t)grow*Ni + gcol] = v;
        } else {
          ((float*)outp)[(size_t)grow*Ni + gcol] = v;
        }
      }
    }
  }
}

// ---------------- LayerNorm over 768, one wave per row --------------------------
__global__ __launch_bounds__(256) void k_ln(const float* __restrict__ h, const float* __restrict__ gam,
    const float* __restrict__ bet, hbf* __restrict__ hn){
  const int tid = threadIdx.x, lane = tid & 63, wave = tid >> 6;
  const int row = blockIdx.x*4 + wave;
  const float* hr = h + (size_t)row*768;
  const int off = lane*4;
  float4 v0 = *(const float4*)(hr + off);
  float4 v1 = *(const float4*)(hr + 256 + off);
  float4 v2 = *(const float4*)(hr + 512 + off);
  float s = v0.x+v0.y+v0.z+v0.w + v1.x+v1.y+v1.z+v1.w + v2.x+v2.y+v2.z+v2.w;
  s = wred(s);
  const float mu = s*(1.f/768.f);
  float q = 0.f;
  q += (v0.x-mu)*(v0.x-mu); q += (v0.y-mu)*(v0.y-mu); q += (v0.z-mu)*(v0.z-mu); q += (v0.w-mu)*(v0.w-mu);
  q += (v1.x-mu)*(v1.x-mu); q += (v1.y-mu)*(v1.y-mu); q += (v1.z-mu)*(v1.z-mu); q += (v1.w-mu)*(v1.w-mu);
  q += (v2.x-mu)*(v2.x-mu); q += (v2.y-mu)*(v2.y-mu); q += (v2.z-mu)*(v2.z-mu); q += (v2.w-mu)*(v2.w-mu);
  q = wred(q);
  const float rs = 1.f/sqrtf(q*(1.f/768.f) + 1e-5f);
  float4 g0 = *(const float4*)(gam + off), g1 = *(const float4*)(gam + 256 + off), g2 = *(const float4*)(gam + 512 + off);
  float4 t0 = *(const float4*)(bet + off), t1 = *(const float4*)(bet + 256 + off), t2 = *(const float4*)(bet + 512 + off);
  hbf* o = hn + (size_t)row*768;
  o[off+0] = __float2bfloat16((v0.x-mu)*rs*g0.x + t0.x);
  o[off+1] = __float2bfloat16((v0.y-mu)*rs*g0.y + t0.y);
  o[off+2] = __float2bfloat16((v0.z-mu)*rs*g0.z + t0.z);
  o[off+3] = __float2bfloat16((v0.w-mu)*rs*g0.w + t0.w);
  o[256+off+0] = __float2bfloat16((v1.x-mu)*rs*g1.x + t1.x);
  o[256+off+1] = __float2bfloat16((v1.y-mu)*rs*g1.y + t1.y);
  o[256+off+2] = __float2bfloat16((v1.z-mu)*rs*g1.z + t1.z);
  o[256+off+3] = __float2bfloat16((v1.w-mu)*rs*g1.w + t1.w);
  o[512+off+0] = __float2bfloat16((v2.x-mu)*rs*g2.x + t2.x);
  o[512+off+1] = __float2bfloat16((v2.y-mu)*rs*g2.y + t2.y);
  o[512+off+2] = __float2bfloat16((v2.z-mu)*rs*g2.z + t2.z);
  o[512+off+3] = __float2bfloat16((v2.w-mu)*rs*g2.w + t2.w);
}

// ---------------- head: normalize tok, grouped cosine logits, cls ---------------
__global__ __launch_bounds__(256) void k_head(const float* __restrict__ tok, const float* __restrict__ ce,
    const float* __restrict__ clsW, const float* __restrict__ clsb, const float* __restrict__ lgs,
    float* __restrict__ out){
  __shared__ float tkn[7*512];
  __shared__ float il[40];
  const int tid = threadIdx.x, lane = tid & 63, wave = tid >> 6;
  const int b = blockIdx.x;
  const float ls = lgs[0];
  for (int g = wave; g < 7; g += 4){
    const float* tr = tok + (size_t)(b*7 + g)*512;
    float4 u0 = *(const float4*)(tr + (lane<<3));
    float4 u1 = *(const float4*)(tr + (lane<<3) + 4);
    float s = d4(u0,u0) + d4(u1,u1);
    s = wred(s);
    const float inv = 1.f/sqrtf(s);
    float* dst = &tkn[g*512 + (lane<<3)];
    dst[0] = u0.x*inv; dst[1] = u0.y*inv; dst[2] = u0.z*inv; dst[3] = u0.w*inv;
    dst[4] = u1.x*inv; dst[5] = u1.y*inv; dst[6] = u1.z*inv; dst[7] = u1.w*inv;
  }
  __syncthreads();
  for (int c = wave; c < 34; c += 4){
    const int g = (c < 30) ? (c/5) : 6;
    const float* tp = &tkn[g*512 + (lane<<3)];
    const float* cp = ce + (size_t)c*512 + (lane<<3);
    float s = tp[0]*cp[0] + tp[1]*cp[1] + tp[2]*cp[2] + tp[3]*cp[3]
            + tp[4]*cp[4] + tp[5]*cp[5] + tp[6]*cp[6] + tp[7]*cp[7];
    s = wred(s);
    if (lane == 0){
      const float v = ls*s;
      il[c] = v;
      out[1792 + b*34 + c] = v;
    }
  }
  __syncthreads();
  if (tid < 7){
    float s = clsb[tid];
    for (int c = 0; c < 34; ++c) s += il[c]*clsW[c*7 + tid];
    out[b*7 + tid] = s;
  }
}

// ---------------- finalize scalars ----------------------------------------------
__global__ void k_fin(const float* __restrict__ scal, float* __restrict__ out){
  if (threadIdx.x == 0){
    out[10496] = 2.f*scal[0]/(float)(256*196*768);
    out[10497] = scal[1]*(1.f/256.f);
  }
}

extern "C" void kernel_launch(void* const* d_in, const int* in_sizes, int n_in,
                              void* d_out, int out_size, void* d_ws, size_t ws_size,
                              hipStream_t stream) {
  (void)in_sizes; (void)n_in; (void)out_size; (void)ws_size;
  const float* x    = (const float*)d_in[0];
  const float* vqcb = (const float*)d_in[1];
  const float* agcb = (const float*)d_in[2];
  const float* W1   = (const float*)d_in[3];
  const float* b1   = (const float*)d_in[4];
  const float* W2   = (const float*)d_in[5];
  const float* b2   = (const float*)d_in[6];
  const float* gam  = (const float*)d_in[7];
  const float* bet  = (const float*)d_in[8];
  const float* Wp   = (const float*)d_in[9];
  const float* ce   = (const float*)d_in[10];
  const float* clsW = (const float*)d_in[11];
  const float* clsb = (const float*)d_in[12];
  const float* lgs  = (const float*)d_in[13];
  float* out = (float*)d_out;
  char* w = (char*)d_ws;

  // workspace layout (~50 MB): scalars | G (reused later for MLP temps) | aggbf | W1t | W2t | Wpt
  float* scal  = (float*)w;
  float* G     = (float*)(w + 256);
  hbf*   aggbf = (hbf*)(w + 39338240ULL);
  hbf*   W1t   = (hbf*)(w + 42090752ULL);
  hbf*   W2t   = (hbf*)(w + 46809344ULL);
  hbf*   Wpt   = (hbf*)(w + 51527936ULL);
  // reuse of G region (G is dead after k_eigen; all consumers run after it):
  hbf*   h1    = (hbf*)(w + 256);
  float* hbuf  = (float*)(w + 256 + 16777216ULL);
  hbf*   hn    = (hbf*)(w + 256 + 25165824ULL);
  float* tok   = (float*)(w + 256 + 29360128ULL);

  k_init<<<dim3(1), dim3(64), 0, stream>>>(scal);
  k_dist<<<dim3(256), dim3(512), 0, stream>>>(x, vqcb, agcb, aggbf, scal);
  k_gram<<<dim3(256), dim3(512), 0, stream>>>(x, G);
  const int EIG_SMEM = 39368*4; // 157,472 B
  hipFuncSetAttribute((const void*)k_eigen, hipFuncAttributeMaxDynamicSharedMemorySize, EIG_SMEM);
  k_eigen<<<dim3(256), dim3(1024), EIG_SMEM, stream>>>(G, scal);
  k_tr<<<dim3(96,24), dim3(256), 0, stream>>>(W1, W1t, 768, 3072);
  k_tr<<<dim3(24,96), dim3(256), 0, stream>>>(W2, W2t, 3072, 768);
  k_tr<<<dim3(16,24), dim3(256), 0, stream>>>(Wp, Wpt, 768, 512);
  k_gemm<1><<<dim3(48,28), dim3(256), 0, stream>>>(aggbf, W1t, b1, (void*)h1, 1792, 3072, 768);
  k_gemm<2><<<dim3(12,28), dim3(256), 0, stream>>>(h1, W2t, b2, (void*)hbuf, 1792, 768, 3072);
  k_ln<<<dim3(448), dim3(256), 0, stream>>>(hbuf, gam, bet, hn);
  k_gemm<3><<<dim3(8,28), dim3(256), 0, stream>>>(hn, Wpt, nullptr, (void*)tok, 1792, 512, 768);
  k_head<<<dim3(256), dim3(256), 0, stream>>>(tok, ce, clsW, clsb, lgs, out);
  k_fin<<<dim3(1), dim3(64), 0, stream>>>(scal, out);
}

// Round 8
// 1048.821 us; speedup vs baseline: 1.8210x; 1.0623x over previous
//
#include <hip/hip_runtime.h>
#include <hip/hip_bf16.h>
#include <math.h>

using hbf = __hip_bfloat16;
typedef __bf16 bf16x8 __attribute__((ext_vector_type(8)));
typedef float f32x4 __attribute__((ext_vector_type(4)));

// within-16-lane rotate-reduce on the VALU (DPP row_ror) — no LDS traffic
__device__ inline float r16d(float v){
  int x;
  x = __builtin_bit_cast(int, v);
  v += __builtin_bit_cast(float, __builtin_amdgcn_mov_dpp(x, 0x121, 0xf, 0xf, true)); // ror:1
  x = __builtin_bit_cast(int, v);
  v += __builtin_bit_cast(float, __builtin_amdgcn_mov_dpp(x, 0x122, 0xf, 0xf, true)); // ror:2
  x = __builtin_bit_cast(int, v);
  v += __builtin_bit_cast(float, __builtin_amdgcn_mov_dpp(x, 0x124, 0xf, 0xf, true)); // ror:4
  x = __builtin_bit_cast(int, v);
  v += __builtin_bit_cast(float, __builtin_amdgcn_mov_dpp(x, 0x128, 0xf, 0xf, true)); // ror:8
  return v;
}
__device__ inline float wred(float v){
  v = r16d(v);
  v += __shfl_xor(v, 16);
  v += __shfl_xor(v, 32);
  return v;
}
__device__ inline float fast_rcp(float x){
  float r; asm("v_rcp_f32 %0, %1" : "=v"(r) : "v"(x)); return r;
}
__device__ inline float d4(const float4& a, const float4& b){
  return a.x*b.x + a.y*b.y + a.z*b.z + a.w*b.w;
}

// ---------------- init: zero the two accumulators (ws is poisoned 0xAA once) ----
__global__ void k_init(float* scal){
  if (threadIdx.x < 2) scal[threadIdx.x] = 0.f;
}

// ---------------- fused distances / softmax / agg / vq loss --------------------
__global__ __launch_bounds__(512) void k_dist(const float* __restrict__ x,
    const float* __restrict__ vqcb, const float* __restrict__ agcb,
    hbf* __restrict__ aggbf, float* __restrict__ scal){
  __shared__ float cA[5376];
  __shared__ float cV[5376];
  __shared__ float sqA[7], sqV[7];
  const int tid = threadIdx.x, lane = tid & 63, wave = tid >> 6;
  const int b = blockIdx.x;
  for (int i = tid; i < 5376; i += 512){ cA[i] = agcb[i]; cV[i] = vqcb[i]; }
  __syncthreads();
  {
    int grp = tid >> 4, l16 = tid & 15;
    if (grp < 14){
      const float* s = (grp < 7) ? &cA[grp*768] : &cV[(grp-7)*768];
      float acc = 0.f;
      for (int j = l16; j < 768; j += 16) acc += s[j]*s[j];
      acc = r16d(acc);
      if (l16 == 0){ if (grp < 7) sqA[grp] = acc; else sqV[grp-7] = acc; }
    }
  }
  __syncthreads();
  float sqAr[7], sqVr[7];
#pragma unroll
  for (int k = 0; k < 7; ++k){ sqAr[k] = sqA[k]; sqVr[k] = sqV[k]; }

  float4 aR[7][3];
#pragma unroll
  for (int k = 0; k < 7; ++k)
#pragma unroll
    for (int c = 0; c < 3; ++c) aR[k][c] = make_float4(0.f,0.f,0.f,0.f);
  float loss = 0.f;

  const float* xb = x + (size_t)b*196*768;
  float4 cx0, cx1, cx2, nx0, nx1, nx2;
  { const float* p = xb + (size_t)wave*768 + (lane<<2);
    cx0 = *(const float4*)(p); cx1 = *(const float4*)(p+256); cx2 = *(const float4*)(p+512); }
  for (int it = 0; it < 25; ++it){
    const int n = it*8 + wave;
    const int nn = n + 8;
    if (nn < 196){
      const float* p = xb + (size_t)nn*768 + (lane<<2);
      nx0 = *(const float4*)(p); nx1 = *(const float4*)(p+256); nx2 = *(const float4*)(p+512);
    }
    if (n < 196){
      float xsq = d4(cx0,cx0)+d4(cx1,cx1)+d4(cx2,cx2);
      float dA[7], dV[7];
#pragma unroll
      for (int k = 0; k < 7; ++k){
        const float4* pa = (const float4*)&cA[k*768];
        const float4* pv = (const float4*)&cV[k*768];
        float4 a0 = pa[lane], a1 = pa[64+lane], a2 = pa[128+lane];
        float4 q0 = pv[lane], q1 = pv[64+lane], q2 = pv[128+lane];
        dA[k] = d4(cx0,a0)+d4(cx1,a1)+d4(cx2,a2);
        dV[k] = d4(cx0,q0)+d4(cx1,q1)+d4(cx2,q2);
      }
      xsq = wred(xsq);
#pragma unroll
      for (int k = 0; k < 7; ++k){ dA[k] = wred(dA[k]); dV[k] = wred(dV[k]); }
      float lg[7], mx = -1e30f;
#pragma unroll
      for (int k = 0; k < 7; ++k){ lg[k] = 2.f*dA[k] - sqAr[k]; mx = fmaxf(mx, lg[k]); }
      float pr[7], ssum = 0.f;
#pragma unroll
      for (int k = 0; k < 7; ++k){ pr[k] = expf(lg[k]-mx); ssum += pr[k]; }
      const float inv = 1.f/ssum;
      float mn = 1e30f;
#pragma unroll
      for (int k = 0; k < 7; ++k) mn = fminf(mn, sqVr[k] - 2.f*dV[k]);
      loss += xsq + mn;
#pragma unroll
      for (int k = 0; k < 7; ++k){
        const float w = pr[k]*inv;
        aR[k][0].x += w*cx0.x; aR[k][0].y += w*cx0.y; aR[k][0].z += w*cx0.z; aR[k][0].w += w*cx0.w;
        aR[k][1].x += w*cx1.x; aR[k][1].y += w*cx1.y; aR[k][1].z += w*cx1.z; aR[k][1].w += w*cx1.w;
        aR[k][2].x += w*cx2.x; aR[k][2].y += w*cx2.y; aR[k][2].z += w*cx2.z; aR[k][2].w += w*cx2.w;
      }
    }
    cx0 = nx0; cx1 = nx1; cx2 = nx2;
  }
  __syncthreads();
  for (int i = tid; i < 5376; i += 512) cA[i] = 0.f;
  __syncthreads();
  for (int w = 0; w < 8; ++w){
    if (wave == w){
#pragma unroll
      for (int k = 0; k < 7; ++k)
#pragma unroll
        for (int c = 0; c < 3; ++c){
          float* p = &cA[k*768 + c*256 + (lane<<2)];
          p[0] += aR[k][c].x; p[1] += aR[k][c].y; p[2] += aR[k][c].z; p[3] += aR[k][c].w;
        }
    }
    __syncthreads();
  }
  for (int i = tid; i < 5376; i += 512) aggbf[(size_t)b*5376 + i] = __float2bfloat16(cA[i]);
  if (lane == 0) atomicAdd(&scal[0], loss);
}

// ---------------- Gram: G = X Xtr per batch, bf16 MFMA, X staged in LDS --------
__global__ __launch_bounds__(512) void k_gram(const float* __restrict__ x, float* __restrict__ G){
  __shared__ hbf Xs[208*104];
  const int tid = threadIdx.x, lane = tid & 63, wave = tid >> 6;
  const int b = blockIdx.x;
  const int l15 = lane & 15;
  const int fr0 = wave, fr1 = wave + 8;
  const bool f1 = (fr1 < 13);
  f32x4 acc0[13] = {};
  f32x4 acc1[13] = {};
  const float* xb = x + (size_t)b*196*768;
  for (int kc = 0; kc < 8; ++kc){
    __syncthreads();
    for (int u = tid; u < 4992; u += 512){
      const int r = u / 24, c4 = u - r*24;
      ushort4 val;
      if (r < 196){
        float4 f = *(const float4*)(xb + (size_t)r*768 + kc*96 + c4*4);
        hbf t0 = __float2bfloat16(f.x), t1 = __float2bfloat16(f.y);
        hbf t2 = __float2bfloat16(f.z), t3 = __float2bfloat16(f.w);
        val.x = *(const unsigned short*)&t0; val.y = *(const unsigned short*)&t1;
        val.z = *(const unsigned short*)&t2; val.w = *(const unsigned short*)&t3;
      } else { val.x = 0; val.y = 0; val.z = 0; val.w = 0; }
      *(ushort4*)&Xs[r*104 + c4*4] = val;
    }
    __syncthreads();
#pragma unroll
    for (int kk = 0; kk < 3; ++kk){
      const int ko = kk*32 + (lane>>4)*8;
      bf16x8 a0 = *(const bf16x8*)&Xs[(fr0*16 + l15)*104 + ko];
      bf16x8 a1 = f1 ? *(const bf16x8*)&Xs[(fr1*16 + l15)*104 + ko] : a0;
#pragma unroll
      for (int fc = 0; fc < 13; ++fc){
        bf16x8 bb = *(const bf16x8*)&Xs[(fc*16 + l15)*104 + ko];
        acc0[fc] = __builtin_amdgcn_mfma_f32_16x16x32_bf16(a0, bb, acc0[fc], 0, 0, 0);
        if (f1) acc1[fc] = __builtin_amdgcn_mfma_f32_16x16x32_bf16(a1, bb, acc1[fc], 0, 0, 0);
      }
    }
  }
  const size_t gb = (size_t)b*38416;
  const int cr = (lane>>4)*4;
#pragma unroll
  for (int fc = 0; fc < 13; ++fc){
    const int gc = fc*16 + l15;
    if (gc < 196){
#pragma unroll
      for (int r = 0; r < 4; ++r){
        const int gr = fr0*16 + cr + r;
        if (gr < 196) G[gb + (size_t)gr*196 + gc] = acc0[fc][r];
      }
      if (f1){
#pragma unroll
        for (int r = 0; r < 4; ++r){
          const int gr = fr1*16 + cr + r;
          if (gr < 196) G[gb + (size_t)gr*196 + gc] = acc1[fc][r];
        }
      }
    }
  }
}

// ---------------- eigen: Householder tridiag in LDS + Sturm bisection ----------
// Main steps (m>64): 16 waves, 2 barriers, branchy hoists, DPP reductions,
// register-cached row scalars, invariant ww[<base]=0 (maskless w-hoist).
// Tail steps (m<=64): single wave, barrier-free.
#define FOLD4(vv4) { vv4.x = (oc==0)? v0 : vv4.x; vv4.y = (oc==1)? v0 : vv4.y; \
                     vv4.z = (oc==2)? v0 : vv4.z; vv4.w = (oc==3)? v0 : vv4.w; }
#define VHOIST(colc, out) { \
  const int col_ = (colc) + jc4; \
  const float4 xv_ = *(const float4*)(rowk + col_); \
  float4 vp_; \
  if (col_ > base){ vp_ = xv_; } \
  else if (col_ + 3 <= base){ vp_ = make_float4(0.f,0.f,0.f,0.f); } \
  else { vp_.x = 0.f; \
         vp_.y = (col_+1 > base) ? xv_.y : 0.f; \
         vp_.z = (col_+2 > base) ? xv_.z : 0.f; \
         vp_.w = xv_.w; } \
  out = vp_; sig += vp_.x*vp_.x + vp_.y*vp_.y + vp_.z*vp_.z + vp_.w*vp_.w; }

__global__ __launch_bounds__(1024) void k_eigen(const float* __restrict__ G, float* __restrict__ scal){
  extern __shared__ float S[];
  float* A   = S;             // 38416 (+80 zeroed pad)
  float* ww  = S + 38496;     // 256
  float* dd  = S + 38752;     // 200
  float* ee  = S + 38952;     // 200
  float* e2  = S + 39152;     // 200
  float* red2= S + 39352;     // 16 (16B-aligned)
  const int n = 196;
  const int tid = threadIdx.x, lane = tid & 63, wave = tid >> 6;
  const int grp = lane >> 4, c16 = lane & 15;
  const int jc4 = c16 << 2;
  const int rbase = (wave << 2) + grp;
  const int b = blockIdx.x;
  {
    const float4* Gv = (const float4*)(G + (size_t)b*38416);
    float4* Av = (float4*)A;
    for (int u = tid; u < 9604; u += 1024) Av[u] = Gv[u];
    if (tid < 80) S[38416 + tid] = 0.f;
    if (tid < 256) ww[tid] = 0.f;
  }
  __syncthreads();
  // ================= main steps: k = 0..130 (m = 195..65) =================
  for (int k = 0; k <= 130; ++k){
    const int base = k + 1, m = n - 1 - k;
    const float* rowk = &A[(size_t)k*196];
    const float x0 = rowk[base];
    if (tid == 0) ww[k] = 0.f;                 // maintain ww[<base]==0
    float4 v4_0, v4_1, v4_2, v4_3;
    float sig = 0.f;
    VHOIST(0,   v4_0)
    VHOIST(64,  v4_1)
    VHOIST(128, v4_2)
    {   // p=3: cols 192..255; base<=131 => keep-all, but only c16==0 is in-row
      const int col_ = 192 + jc4;
      const float4 xv_ = *(const float4*)(rowk + col_);
      if (c16 == 0){ v4_3 = xv_; sig += xv_.x*xv_.x + xv_.y*xv_.y + xv_.z*xv_.z + xv_.w*xv_.w; }
      else v4_3 = make_float4(0.f,0.f,0.f,0.f);
    }
    sig = r16d(sig);
    float tau = 0.f, v0 = 0.f, alpha = x0;
    if (sig > 1e-20f){
      const float mu = sqrtf(x0*x0 + sig);
      alpha = (x0 > 0.f) ? -mu : mu;
      v0 = x0 - alpha;
      tau = 2.f/(sig + v0*v0);
    }
    if (tid == 0) ee[k] = alpha;
    if (c16 == ((base >> 2) & 15)){
      const int oc = base & 3;
      const int op = base >> 6;                // 0..2 in main
      if (op == 0){ FOLD4(v4_0) } else if (op == 1){ FOLD4(v4_1) } else { FOLD4(v4_2) }
    }
    const int p0 = base >> 6;
    float vr_0=0.f, vr_1=0.f, vr_2=0.f, vr_3=0.f;
    float wr_0=0.f, wr_1=0.f, wr_2=0.f, wr_3=0.f;
    if (tau != 0.f){
      float cpart = 0.f;
#define MV_T(T, VRV, WRV) { \
      const int i_ = ((T)<<6) + rbase; \
      if (i_ < m){ \
        const float* Ar = &A[(size_t)(base+i_)*196]; \
        float acc = 0.f; \
        if (0 >= p0){ const float4 a = *(const float4*)(Ar + jc4);       acc += d4(a, v4_0); } \
        if (1 >= p0){ const float4 a = *(const float4*)(Ar + 64 + jc4);  acc += d4(a, v4_1); } \
        if (2 >= p0){ const float4 a = *(const float4*)(Ar + 128 + jc4); acc += d4(a, v4_2); } \
        { const float4 a = *(const float4*)(Ar + 192 + jc4);             acc += d4(a, v4_3); } \
        acc = r16d(acc); \
        WRV = tau*acc; \
        VRV = (i_ == 0) ? v0 : rowk[base+i_]; \
        cpart += VRV*WRV; \
        if (c16 == 0) ww[base+i_] = WRV; } }
      MV_T(0, vr_0, wr_0)
      MV_T(1, vr_1, wr_1)
      MV_T(2, vr_2, wr_2)
      MV_T(3, vr_3, wr_3)
#undef MV_T
      cpart += __shfl_xor(cpart, 16);
      cpart += __shfl_xor(cpart, 32);
      if (lane == 0) red2[wave] = cpart;
    }
    __syncthreads();                           // B1
    if (tau != 0.f){
      const float4* r2 = (const float4*)red2;
      const float4 q0 = r2[0], q1 = r2[1], q2 = r2[2], q3 = r2[3];
      const float vtw = (q0.x+q0.y+q0.z+q0.w) + (q1.x+q1.y+q1.z+q1.w)
                      + (q2.x+q2.y+q2.z+q2.w) + (q3.x+q3.y+q3.z+q3.w);
      const float c2 = 0.5f*tau*vtw;
      float4 w4_0, w4_1, w4_2, w4_3;
      { const float4 t4 = *(const float4*)(ww + jc4);
        w4_0.x = t4.x - c2*v4_0.x; w4_0.y = t4.y - c2*v4_0.y; w4_0.z = t4.z - c2*v4_0.z; w4_0.w = t4.w - c2*v4_0.w; }
      { const float4 t4 = *(const float4*)(ww + 64 + jc4);
        w4_1.x = t4.x - c2*v4_1.x; w4_1.y = t4.y - c2*v4_1.y; w4_1.z = t4.z - c2*v4_1.z; w4_1.w = t4.w - c2*v4_1.w; }
      { const float4 t4 = *(const float4*)(ww + 128 + jc4);
        w4_2.x = t4.x - c2*v4_2.x; w4_2.y = t4.y - c2*v4_2.y; w4_2.z = t4.z - c2*v4_2.z; w4_2.w = t4.w - c2*v4_2.w; }
      { const float4 t4 = *(const float4*)(ww + 192 + jc4);
        w4_3.x = t4.x - c2*v4_3.x; w4_3.y = t4.y - c2*v4_3.y; w4_3.z = t4.z - c2*v4_3.z; w4_3.w = t4.w - c2*v4_3.w; }
#define UP_T(T, VRV, WRV) { \
      const int i_ = ((T)<<6) + rbase; \
      if (i_ < m){ \
        const float vi = VRV; \
        const float wi = WRV - c2*vi; \
        float* Ar = &A[(size_t)(base+i_)*196]; \
        if (0 >= p0){ float4 a = *(const float4*)(Ar + jc4); \
          a.x -= vi*w4_0.x + wi*v4_0.x; a.y -= vi*w4_0.y + wi*v4_0.y; \
          a.z -= vi*w4_0.z + wi*v4_0.z; a.w -= vi*w4_0.w + wi*v4_0.w; \
          *(float4*)(Ar + jc4) = a; } \
        if (1 >= p0){ float4 a = *(const float4*)(Ar + 64 + jc4); \
          a.x -= vi*w4_1.x + wi*v4_1.x; a.y -= vi*w4_1.y + wi*v4_1.y; \
          a.z -= vi*w4_1.z + wi*v4_1.z; a.w -= vi*w4_1.w + wi*v4_1.w; \
          *(float4*)(Ar + 64 + jc4) = a; } \
        if (2 >= p0){ float4 a = *(const float4*)(Ar + 128 + jc4); \
          a.x -= vi*w4_2.x + wi*v4_2.x; a.y -= vi*w4_2.y + wi*v4_2.y; \
          a.z -= vi*w4_2.z + wi*v4_2.z; a.w -= vi*w4_2.w + wi*v4_2.w; \
          *(float4*)(Ar + 128 + jc4) = a; } \
        if (c16 == 0){ float4 a = *(const float4*)(Ar + 192); \
          a.x -= vi*w4_3.x + wi*v4_3.x; a.y -= vi*w4_3.y + wi*v4_3.y; \
          a.z -= vi*w4_3.z + wi*v4_3.z; a.w -= vi*w4_3.w + wi*v4_3.w; \
          *(float4*)(Ar + 192) = a; } } }
      UP_T(0, vr_0, wr_0)
      UP_T(1, vr_1, wr_1)
      UP_T(2, vr_2, wr_2)
      UP_T(3, vr_3, wr_3)
#undef UP_T
    }
    __syncthreads();                           // B2
  }
  // ================= tail steps: k = 131..193 (m = 64..2), wave 0 only =====
  if (wave == 0){
    float vrT[16], wrT[16];
    for (int k = 131; k <= n-3; ++k){
      const int base = k + 1, m = n - 1 - k;   // m <= 64
      const float* rowk = &A[(size_t)k*196];
      const float x0 = rowk[base];
      if (lane == 0) ww[k] = 0.f;
      float4 v4_2, v4_3;
      float sig = 0.f;
      VHOIST(128, v4_2)
      {
        const int col_ = 192 + jc4;
        float4 vp_ = make_float4(0.f,0.f,0.f,0.f);
        if (c16 == 0){
          const float4 xv_ = *(const float4*)(rowk + col_);
          if (col_ > base){ vp_ = xv_; }
          else { vp_.x = 0.f;
                 vp_.y = (col_+1 > base) ? xv_.y : 0.f;
                 vp_.z = (col_+2 > base) ? xv_.z : 0.f;
                 vp_.w = xv_.w; }
        }
        v4_3 = vp_; sig += vp_.x*vp_.x + vp_.y*vp_.y + vp_.z*vp_.z + vp_.w*vp_.w;
      }
      sig = r16d(sig);
      float tau = 0.f, v0 = 0.f, alpha = x0;
      if (sig > 1e-20f){
        const float mu = sqrtf(x0*x0 + sig);
        alpha = (x0 > 0.f) ? -mu : mu;
        v0 = x0 - alpha;
        tau = 2.f/(sig + v0*v0);
      }
      if (lane == 0) ee[k] = alpha;
      if (c16 == ((base >> 2) & 15)){
        const int oc = base & 3;
        if ((base >> 6) == 2){ FOLD4(v4_2) } else { FOLD4(v4_3) }
      }
      if (tau != 0.f){
        float cpart = 0.f;
#pragma unroll
        for (int t = 0; t < 16; ++t){
          const int i_ = (t << 2) + grp;
          float vrv = 0.f, wrv = 0.f;
          if (i_ < m){
            const float* Ar = &A[(size_t)(base+i_)*196];
            const float4 a2 = *(const float4*)(Ar + 128 + jc4);
            const float4 a3 = *(const float4*)(Ar + 192 + jc4);
            float acc = d4(a2, v4_2) + d4(a3, v4_3);
            acc = r16d(acc);
            wrv = tau*acc;
            vrv = (i_ == 0) ? v0 : rowk[base+i_];
            cpart += vrv*wrv;
            if (c16 == 0) ww[base+i_] = wrv;
          }
          vrT[t] = vrv; wrT[t] = wrv;
        }
        cpart += __shfl_xor(cpart, 16);
        cpart += __shfl_xor(cpart, 32);
        const float c2 = 0.5f*tau*cpart;
        __threadfence_block();                 // ww writes -> cross-lane reads
        float4 w4_2, w4_3;
        { const float4 t4 = *(const float4*)(ww + 128 + jc4);
          w4_2.x = t4.x - c2*v4_2.x; w4_2.y = t4.y - c2*v4_2.y; w4_2.z = t4.z - c2*v4_2.z; w4_2.w = t4.w - c2*v4_2.w; }
        { const float4 t4 = *(const float4*)(ww + 192 + jc4);
          w4_3.x = t4.x - c2*v4_3.x; w4_3.y = t4.y - c2*v4_3.y; w4_3.z = t4.z - c2*v4_3.z; w4_3.w = t4.w - c2*v4_3.w; }
#pragma unroll
        for (int t = 0; t < 16; ++t){
          const int i_ = (t << 2) + grp;
          if (i_ < m){
            const float vi = vrT[t];
            const float wi = wrT[t] - c2*vi;
            float* Ar = &A[(size_t)(base+i_)*196];
            float4 a = *(const float4*)(Ar + 128 + jc4);
            a.x -= vi*w4_2.x + wi*v4_2.x; a.y -= vi*w4_2.y + wi*v4_2.y;
            a.z -= vi*w4_2.z + wi*v4_2.z; a.w -= vi*w4_2.w + wi*v4_2.w;
            *(float4*)(Ar + 128 + jc4) = a;
            if (c16 == 0){
              float4 a3 = *(const float4*)(Ar + 192);
              a3.x -= vi*w4_3.x + wi*v4_3.x; a3.y -= vi*w4_3.y + wi*v4_3.y;
              a3.z -= vi*w4_3.z + wi*v4_3.z; a3.w -= vi*w4_3.w + wi*v4_3.w;
              *(float4*)(Ar + 192) = a3;
            }
          }
        }
        __threadfence_block();                 // A writes -> next-step reads
      }
    }
  }
  __syncthreads();
  if (tid < n) dd[tid] = A[(size_t)tid*196 + tid];
  if (tid == 0) ee[n-2] = A[(size_t)(n-1)*196 + (n-2)];
  __syncthreads();
  if (tid < n-1) e2[tid] = ee[tid]*ee[tid];
  __syncthreads();
  // Gershgorin bounds
  float lo = 1e30f, hi = -1e30f;
  if (tid < n){
    const float rr = ((tid > 0) ? fabsf(ee[tid-1]) : 0.f) + ((tid < n-1) ? fabsf(ee[tid]) : 0.f);
    lo = dd[tid] - rr; hi = dd[tid] + rr;
  }
  {
    float l2 = lo, h2 = hi;
#pragma unroll
    for (int o = 32; o > 0; o >>= 1){
      l2 = fminf(l2, __shfl_xor(l2, o));
      h2 = fmaxf(h2, __shfl_xor(h2, o));
    }
    if (lane == 0){ ww[wave] = l2; red2[wave] = h2; }
  }
  __syncthreads();
  float glo = ww[0], ghi = red2[0];
#pragma unroll
  for (int w2 = 1; w2 < 16; ++w2){ glo = fminf(glo, ww[w2]); ghi = fmaxf(ghi, red2[w2]); }
  __syncthreads();
  // Sturm bisection: thread tid finds the tid-th smallest eigenvalue
  float sv = 0.f;
  if (tid < n){
    float lob = glo, hib = ghi;
    for (int it2 = 0; it2 < 26; ++it2){
      const float mid = 0.5f*(lob + hib);
      float q = dd[0] - mid;
      int cnt = (q < 0.f) ? 1 : 0;
      for (int i = 1; i < n; ++i){
        const float r = fast_rcp(q);
        q = (dd[i] - mid) - e2[i-1]*r;
        q = (fabsf(q) < 1e-6f) ? -1e-6f : q;
        cnt += (q < 0.f) ? 1 : 0;
      }
      if (cnt <= tid) lob = mid; else hib = mid;
    }
    sv = sqrtf(fmaxf(0.5f*(lob + hib), 0.f));
  }
  __syncthreads();
  if (tid < n) ww[tid] = sv;
  __syncthreads();
  if (tid == 0){
    float tot = 0.f;
    for (int i = 0; i < n; ++i) tot += ww[i];
    const float thr = 0.99f*tot;
    float cs = 0.f; int rank = 0;
    for (int i = n-1; i >= 0; --i){ cs += ww[i]; rank += (cs <= thr) ? 1 : 0; }
    atomicAdd(&scal[1], (float)rank);
  }
}

// ---------------- transpose + f32->bf16 for weights ----------------------------
__global__ __launch_bounds__(256) void k_tr(const float* __restrict__ in, hbf* __restrict__ outp,
                                            int Rr, int Cc){
  __shared__ float t[32][33];
  const int tid = threadIdx.x;
  const int lc = tid & 31, lr = tid >> 5;
  const int c0 = blockIdx.x*32, r0 = blockIdx.y*32;
#pragma unroll
  for (int i = 0; i < 4; ++i)
    t[lr + i*8][lc] = in[(size_t)(r0 + lr + i*8)*Cc + c0 + lc];
  __syncthreads();
#pragma unroll
  for (int i = 0; i < 4; ++i)
    outp[(size_t)(c0 + lr + i*8)*Rr + r0 + lc] = __float2bfloat16(t[lc][lr + i*8]);
}

// ---------------- GEMM: A[M,K] * B^T[N,K], bf16 MFMA 16x16x32, 64x64 tiles ------
template<int EPI>
__global__ __launch_bounds__(256) void k_gemm(const hbf* __restrict__ Aa, const hbf* __restrict__ Bb,
    const float* __restrict__ bias, void* __restrict__ outp, int Mi, int Ni, int Ki){
  __shared__ hbf As[64*72];
  __shared__ hbf Bs[64*72];
  const int tid = threadIdx.x, lane = tid & 63, wave = tid >> 6;
  const int row0 = blockIdx.y*64, col0 = blockIdx.x*64;
  const int m0 = (wave >> 1)*32, n0 = (wave & 1)*32;
  const int l15 = lane & 15, lk = (lane >> 4)*8;
  const int sr = tid >> 3, sc = (tid & 7)*8;
  f32x4 acc00 = {}, acc01 = {}, acc10 = {}, acc11 = {};
  for (int kt = 0; kt < Ki; kt += 64){
    __syncthreads();
    *(uint4*)&As[sr*72 + sc]        = *(const uint4*)&Aa[(size_t)(row0+sr)*Ki + kt + sc];
    *(uint4*)&As[(sr+32)*72 + sc]   = *(const uint4*)&Aa[(size_t)(row0+sr+32)*Ki + kt + sc];
    *(uint4*)&Bs[sr*72 + sc]        = *(const uint4*)&Bb[(size_t)(col0+sr)*Ki + kt + sc];
    *(uint4*)&Bs[(sr+32)*72 + sc]   = *(const uint4*)&Bb[(size_t)(col0+sr+32)*Ki + kt + sc];
    __syncthreads();
#pragma unroll
    for (int kk = 0; kk < 2; ++kk){
      const int ko = kk*32 + lk;
      bf16x8 a0 = *(const bf16x8*)&As[(m0 + l15)*72 + ko];
      bf16x8 a1 = *(const bf16x8*)&As[(m0 + 16 + l15)*72 + ko];
      bf16x8 b0 = *(const bf16x8*)&Bs[(n0 + l15)*72 + ko];
      bf16x8 b1 = *(const bf16x8*)&Bs[(n0 + 16 + l15)*72 + ko];
      acc00 = __builtin_amdgcn_mfma_f32_16x16x32_bf16(a0, b0, acc00, 0, 0, 0);
      acc01 = __builtin_amdgcn_mfma_f32_16x16x32_bf16(a0, b1, acc01, 0, 0, 0);
      acc10 = __builtin_amdgcn_mfma_f32_16x16x32_bf16(a1, b0, acc10, 0, 0, 0);
      acc11 = __builtin_amdgcn_mfma_f32_16x16x32_bf16(a1, b1, acc11, 0, 0, 0);
    }
  }
  const int cr = (lane >> 4)*4;
#pragma unroll
  for (int i = 0; i < 2; ++i){
#pragma unroll
    for (int j = 0; j < 2; ++j){
      f32x4 av = (i == 0) ? ((j == 0) ? acc00 : acc01) : ((j == 0) ? acc10 : acc11);
      const int gcol = col0 + n0 + j*16 + l15;
#pragma unroll
      for (int r = 0; r < 4; ++r){
        const int grow = row0 + m0 + i*16 + cr + r;
        float v = av[r];
        if (EPI == 1){
          v += bias[gcol];
          v = 0.5f*v*(1.f + erff(v*0.70710678118654752f));
          ((hbf*)outp)[(size_t)grow*Ni + gcol] = __float2bfloat16(v);
        } else if (EPI == 2){
          v += bias[gcol];
          ((float*)outp)[(size_t)grow*Ni + gcol] = v;
        } else {
          ((float*)outp)[(size_t)grow*Ni + gcol] = v;
        }
      }
    }
  }
}

// ---------------- LayerNorm over 768, one wave per row --------------------------
__global__ __launch_bounds__(256) void k_ln(const float* __restrict__ h, const float* __restrict__ gam,
    const float* __restrict__ bet, hbf* __restrict__ hn){
  const int tid = threadIdx.x, lane = tid & 63, wave = tid >> 6;
  const int row = blockIdx.x*4 + wave;
  const float* hr = h + (size_t)row*768;
  const int off = lane*4;
  float4 v0 = *(const float4*)(hr + off);
  float4 v1 = *(const float4*)(hr + 256 + off);
  float4 v2 = *(const float4*)(hr + 512 + off);
  float s = v0.x+v0.y+v0.z+v0.w + v1.x+v1.y+v1.z+v1.w + v2.x+v2.y+v2.z+v2.w;
  s = wred(s);
  const float mu = s*(1.f/768.f);
  float q = 0.f;
  q += (v0.x-mu)*(v0.x-mu); q += (v0.y-mu)*(v0.y-mu); q += (v0.z-mu)*(v0.z-mu); q += (v0.w-mu)*(v0.w-mu);
  q += (v1.x-mu)*(v1.x-mu); q += (v1.y-mu)*(v1.y-mu); q += (v1.z-mu)*(v1.z-mu); q += (v1.w-mu)*(v1.w-mu);
  q += (v2.x-mu)*(v2.x-mu); q += (v2.y-mu)*(v2.y-mu); q += (v2.z-mu)*(v2.z-mu); q += (v2.w-mu)*(v2.w-mu);
  q = wred(q);
  const float rs = 1.f/sqrtf(q*(1.f/768.f) + 1e-5f);
  float4 g0 = *(const float4*)(gam + off), g1 = *(const float4*)(gam + 256 + off), g2 = *(const float4*)(gam + 512 + off);
  float4 t0 = *(const float4*)(bet + off), t1 = *(const float4*)(bet + 256 + off), t2 = *(const float4*)(bet + 512 + off);
  hbf* o = hn + (size_t)row*768;
  o[off+0] = __float2bfloat16((v0.x-mu)*rs*g0.x + t0.x);
  o[off+1] = __float2bfloat16((v0.y-mu)*rs*g0.y + t0.y);
  o[off+2] = __float2bfloat16((v0.z-mu)*rs*g0.z + t0.z);
  o[off+3] = __float2bfloat16((v0.w-mu)*rs*g0.w + t0.w);
  o[256+off+0] = __float2bfloat16((v1.x-mu)*rs*g1.x + t1.x);
  o[256+off+1] = __float2bfloat16((v1.y-mu)*rs*g1.y + t1.y);
  o[256+off+2] = __float2bfloat16((v1.z-mu)*rs*g1.z + t1.z);
  o[256+off+3] = __float2bfloat16((v1.w-mu)*rs*g1.w + t1.w);
  o[512+off+0] = __float2bfloat16((v2.x-mu)*rs*g2.x + t2.x);
  o[512+off+1] = __float2bfloat16((v2.y-mu)*rs*g2.y + t2.y);
  o[512+off+2] = __float2bfloat16((v2.z-mu)*rs*g2.z + t2.z);
  o[512+off+3] = __float2bfloat16((v2.w-mu)*rs*g2.w + t2.w);
}

// ---------------- head: normalize tok, grouped cosine logits, cls ---------------
__global__ __launch_bounds__(256) void k_head(const float* __restrict__ tok, const float* __restrict__ ce,
    const float* __restrict__ clsW, const float* __restrict__ clsb, const float* __restrict__ lgs,
    float* __restrict__ out){
  __shared__ float tkn[7*512];
  __shared__ float il[40];
  const int tid = threadIdx.x, lane = tid & 63, wave = tid >> 6;
  const int b = blockIdx.x;
  const float ls = lgs[0];
  for (int g = wave; g < 7; g += 4){
    const float* tr = tok + (size_t)(b*7 + g)*512;
    float4 u0 = *(const float4*)(tr + (lane<<3));
    float4 u1 = *(const float4*)(tr + (lane<<3) + 4);
    float s = d4(u0,u0) + d4(u1,u1);
    s = wred(s);
    const float inv = 1.f/sqrtf(s);
    float* dst = &tkn[g*512 + (lane<<3)];
    dst[0] = u0.x*inv; dst[1] = u0.y*inv; dst[2] = u0.z*inv; dst[3] = u0.w*inv;
    dst[4] = u1.x*inv; dst[5] = u1.y*inv; dst[6] = u1.z*inv; dst[7] = u1.w*inv;
  }
  __syncthreads();
  for (int c = wave; c < 34; c += 4){
    const int g = (c < 30) ? (c/5) : 6;
    const float* tp = &tkn[g*512 + (lane<<3)];
    const float* cp = ce + (size_t)c*512 + (lane<<3);
    float s = tp[0]*cp[0] + tp[1]*cp[1] + tp[2]*cp[2] + tp[3]*cp[3]
            + tp[4]*cp[4] + tp[5]*cp[5] + tp[6]*cp[6] + tp[7]*cp[7];
    s = wred(s);
    if (lane == 0){
      const float v = ls*s;
      il[c] = v;
      out[1792 + b*34 + c] = v;
    }
  }
  __syncthreads();
  if (tid < 7){
    float s = clsb[tid];
    for (int c = 0; c < 34; ++c) s += il[c]*clsW[c*7 + tid];
    out[b*7 + tid] = s;
  }
}

// ---------------- finalize scalars ----------------------------------------------
__global__ void k_fin(const float* __restrict__ scal, float* __restrict__ out){
  if (threadIdx.x == 0){
    out[10496] = 2.f*scal[0]/(float)(256*196*768);
    out[10497] = scal[1]*(1.f/256.f);
  }
}

extern "C" void kernel_launch(void* const* d_in, const int* in_sizes, int n_in,
                              void* d_out, int out_size, void* d_ws, size_t ws_size,
                              hipStream_t stream) {
  (void)in_sizes; (void)n_in; (void)out_size; (void)ws_size;
  const float* x    = (const float*)d_in[0];
  const float* vqcb = (const float*)d_in[1];
  const float* agcb = (const float*)d_in[2];
  const float* W1   = (const float*)d_in[3];
  const float* b1   = (const float*)d_in[4];
  const float* W2   = (const float*)d_in[5];
  const float* b2   = (const float*)d_in[6];
  const float* gam  = (const float*)d_in[7];
  const float* bet  = (const float*)d_in[8];
  const float* Wp   = (const float*)d_in[9];
  const float* ce   = (const float*)d_in[10];
  const float* clsW = (const float*)d_in[11];
  const float* clsb = (const float*)d_in[12];
  const float* lgs  = (const float*)d_in[13];
  float* out = (float*)d_out;
  char* w = (char*)d_ws;

  float* scal  = (float*)w;
  float* G     = (float*)(w + 256);
  hbf*   aggbf = (hbf*)(w + 39338240ULL);
  hbf*   W1t   = (hbf*)(w + 42090752ULL);
  hbf*   W2t   = (hbf*)(w + 46809344ULL);
  hbf*   Wpt   = (hbf*)(w + 51527936ULL);
  hbf*   h1    = (hbf*)(w + 256);
  float* hbuf  = (float*)(w + 256 + 16777216ULL);
  hbf*   hn    = (hbf*)(w + 256 + 25165824ULL);
  float* tok   = (float*)(w + 256 + 29360128ULL);

  k_init<<<dim3(1), dim3(64), 0, stream>>>(scal);
  k_dist<<<dim3(256), dim3(512), 0, stream>>>(x, vqcb, agcb, aggbf, scal);
  k_gram<<<dim3(256), dim3(512), 0, stream>>>(x, G);
  const int EIG_SMEM = 39368*4; // 157,472 B
  hipFuncSetAttribute((const void*)k_eigen, hipFuncAttributeMaxDynamicSharedMemorySize, EIG_SMEM);
  k_eigen<<<dim3(256), dim3(1024), EIG_SMEM, stream>>>(G, scal);
  k_tr<<<dim3(96,24), dim3(256), 0, stream>>>(W1, W1t, 768, 3072);
  k_tr<<<dim3(24,96), dim3(256), 0, stream>>>(W2, W2t, 3072, 768);
  k_tr<<<dim3(16,24), dim3(256), 0, stream>>>(Wp, Wpt, 768, 512);
  k_gemm<1><<<dim3(48,28), dim3(256), 0, stream>>>(aggbf, W1t, b1, (void*)h1, 1792, 3072, 768);
  k_gemm<2><<<dim3(12,28), dim3(256), 0, stream>>>(h1, W2t, b2, (void*)hbuf, 1792, 768, 3072);
  k_ln<<<dim3(448), dim3(256), 0, stream>>>(hbuf, gam, bet, hn);
  k_gemm<3><<<dim3(8,28), dim3(256), 0, stream>>>(hn, Wpt, nullptr, (void*)tok, 1792, 512, 768);
  k_head<<<dim3(256), dim3(256), 0, stream>>>(tok, ce, clsW, clsb, lgs, out);
  k_fin<<<dim3(1), dim3(64), 0, stream>>>(scal, out);
}